// Round 1
// baseline (3508.194 us; speedup 1.0000x reference)
//
#include <hip/hip_runtime.h>
#include <stdint.h>

#define B_    256
#define T_    77
#define E_    1280
#define H_    20
#define T2_   154
#define MTOK  19712   // B_*T_
#define MTOK2 39424   // B_*T2_

typedef float f32x4 __attribute__((ext_vector_type(4)));
typedef short bf16x8 __attribute__((ext_vector_type(8)));

__device__ inline float bf2f(short s) {
    return __uint_as_float(((unsigned)(unsigned short)s) << 16);
}
__device__ inline short f2bf(float f) {
    unsigned u = __float_as_uint(f);
    u += 0x7fff + ((u >> 16) & 1);   // RNE
    return (short)(u >> 16);
}
__device__ inline float gelu_tanh(float x) {   // jax.nn.gelu approximate=True
    float x3 = x * x * x;
    return 0.5f * x * (1.0f + tanhf(0.7978845608028654f * (x + 0.044715f * x3)));
}

// ---------------- fp32 -> bf16 cast ----------------
__global__ void cast_f32_bf16(const float* __restrict__ in, short* __restrict__ out, int n4) {
    int i = blockIdx.x * blockDim.x + threadIdx.x;
    int stride = gridDim.x * blockDim.x;
    for (; i < n4; i += stride) {
        float4 v = reinterpret_cast<const float4*>(in)[i];
        short4 o;
        o.x = f2bf(v.x); o.y = f2bf(v.y); o.z = f2bf(v.z); o.w = f2bf(v.w);
        reinterpret_cast<short4*>(out)[i] = o;
    }
}

// ---------------- bf16 GEMM: C[M,N] = A[M,K] @ W[N,K]^T (+epilogue) -------------
// m97 structure: 128x128 tile, BK=64, 4 waves (each 64x64), global_load_lds w=16.
// EPI: 0 = +bias -> bf16 ; 1 = (+bias)*scale -> bf16 ; 2 = gelu(+bias) -> bf16 ;
//      3 = +bias -> fp32
template<int EPI>
__global__ void gemm_bt(const short* __restrict__ A, const short* __restrict__ W,
                        const float* __restrict__ bias, void* __restrict__ Cout,
                        int K, float scale) {
    const int N = E_;
    __shared__ short Als[128 * 64];
    __shared__ short Bls[128 * 64];
    const int tid  = threadIdx.x;
    const int wave = tid >> 6, lane = tid & 63;
    const int bm = blockIdx.x, bn = blockIdx.y;
    const int wm = (wave >> 1) * 64, wn = (wave & 1) * 64;

    f32x4 acc[4][4] = {};

    const long arow0 = (long)bm * 128;
    const long brow0 = (long)bn * 128;
    const int rsub = lane >> 3;          // 0..7 row within 8-row chunk
    const int col  = (lane & 7) * 8;     // 0..56, 8 bf16 = 16B per lane

    for (int kt = 0; kt < K; kt += 64) {
        __syncthreads();   // prev compute done before overwriting LDS
#pragma unroll
        for (int i = 0; i < 4; ++i) {
            int chunk = i * 4 + wave;          // 0..15, 8 rows each
            int row = chunk * 8 + rsub;
            const short* ga = A + (arow0 + row) * K + kt + col;
            const short* gb = W + (brow0 + row) * K + kt + col;
            __builtin_amdgcn_global_load_lds(
                (const __attribute__((address_space(1))) unsigned int*)ga,
                (__attribute__((address_space(3))) unsigned int*)&Als[chunk * 512], 16, 0, 0);
            __builtin_amdgcn_global_load_lds(
                (const __attribute__((address_space(1))) unsigned int*)gb,
                (__attribute__((address_space(3))) unsigned int*)&Bls[chunk * 512], 16, 0, 0);
        }
        __syncthreads();   // drains vmcnt -> tiles ready
#pragma unroll
        for (int kk = 0; kk < 2; ++kk) {
            bf16x8 af[4], bfr[4];
#pragma unroll
            for (int mi = 0; mi < 4; ++mi)
                af[mi] = *reinterpret_cast<const bf16x8*>(
                    &Als[(wm + mi * 16 + (lane & 15)) * 64 + kk * 32 + (lane >> 4) * 8]);
#pragma unroll
            for (int nj = 0; nj < 4; ++nj)
                bfr[nj] = *reinterpret_cast<const bf16x8*>(
                    &Bls[(wn + nj * 16 + (lane & 15)) * 64 + kk * 32 + (lane >> 4) * 8]);
#pragma unroll
            for (int mi = 0; mi < 4; ++mi)
#pragma unroll
                for (int nj = 0; nj < 4; ++nj)
                    acc[mi][nj] = __builtin_amdgcn_mfma_f32_16x16x32_bf16(
                        af[mi], bfr[nj], acc[mi][nj], 0, 0, 0);
        }
    }

    // epilogue: C/D layout col=lane&15, row=(lane>>4)*4+r  [m89-verified]
#pragma unroll
    for (int mi = 0; mi < 4; ++mi) {
#pragma unroll
        for (int nj = 0; nj < 4; ++nj) {
            int gcol = bn * 128 + wn + nj * 16 + (lane & 15);
            float bv = bias[gcol];
#pragma unroll
            for (int r = 0; r < 4; ++r) {
                long grow = arow0 + wm + mi * 16 + (lane >> 4) * 4 + r;
                float v = acc[mi][nj][r] + bv;
                if (EPI == 1) v *= scale;
                if (EPI == 2) v = gelu_tanh(v);
                if (EPI == 3) ((float*)Cout)[grow * N + gcol] = v;
                else          ((short*)Cout)[grow * N + gcol] = f2bf(v);
            }
        }
    }
}

// ---------------- attention: one block per (b,h) ----------------
// Q,K,V in (B,T,E) bf16 (scale+bias already applied to Q). Writes bf16 into
// CAT (B, 2T, E) at token offset rowoff.
template<bool CAUSAL>
__global__ void attn_kernel(const short* __restrict__ Qm, const short* __restrict__ Km,
                            const short* __restrict__ Vm, short* __restrict__ Cat,
                            int rowoff) {
    __shared__ float Kls[T_][65];   // pad 65: bank = (s+d) % 32, conflict-free
    __shared__ float Vls[T_][65];
    __shared__ float qls[4][64];
    __shared__ float pls[4][128];
    const int bh = blockIdx.x;
    const int b = bh / H_, h = bh % H_;
    const int tid = threadIdx.x, wave = tid >> 6, lane = tid & 63;
    const long base = ((long)b * T_) * E_ + h * 64;

    for (int idx = tid; idx < T_ * 64; idx += 256) {
        int s = idx >> 6, d = idx & 63;
        Kls[s][d] = bf2f(Km[base + (long)s * E_ + d]);
        Vls[s][d] = bf2f(Vm[base + (long)s * E_ + d]);
    }
    __syncthreads();

    const int s1 = lane;
    const bool has2 = (lane + 64) < T_;          // lanes 0..12
    const int s2 = has2 ? lane + 64 : 0;

    for (int t = wave; t < T_; t += 4) {
        qls[wave][lane] = bf2f(Qm[base + (long)t * E_ + lane]);
        asm volatile("s_waitcnt lgkmcnt(0)" ::: "memory");
        __builtin_amdgcn_wave_barrier();

        float a0 = 0.f, a1 = 0.f;
#pragma unroll 16
        for (int d = 0; d < 64; ++d) {
            float qd = qls[wave][d];             // broadcast read
            a0 = fmaf(qd, Kls[s1][d], a0);
            a1 = fmaf(qd, Kls[s2][d], a1);
        }
        bool v1 = CAUSAL ? (s1 <= t) : true;
        bool v2 = has2 && (CAUSAL ? ((lane + 64) <= t) : true);
        float m = fmaxf(v1 ? a0 : -3.0e38f, v2 ? a1 : -3.0e38f);
#pragma unroll
        for (int o = 32; o; o >>= 1) m = fmaxf(m, __shfl_xor(m, o));
        float p0 = v1 ? __expf(a0 - m) : 0.f;
        float p1 = v2 ? __expf(a1 - m) : 0.f;
        float sm = p0 + p1;
#pragma unroll
        for (int o = 32; o; o >>= 1) sm += __shfl_xor(sm, o);
        float inv = 1.0f / sm;
        pls[wave][lane] = p0 * inv;
        pls[wave][lane + 64] = p1 * inv;
        asm volatile("s_waitcnt lgkmcnt(0)" ::: "memory");
        __builtin_amdgcn_wave_barrier();

        float o_ = 0.f;
        for (int s = 0; s < T_; ++s)
            o_ = fmaf(pls[wave][s], Vls[s][lane], o_);   // p broadcast, V 2-way (free)

        Cat[((long)b * T2_ + rowoff + t) * E_ + h * 64 + lane] = f2bf(o_);
        __builtin_amdgcn_wave_barrier();
    }
}

// ---------------- token mixer 1: X2[b,t,e] = gelu(sum_s Y[b,s,e]*zt1w[t,s] + b[t]) ----
__global__ void ztmix1(const short* __restrict__ Y, const float* __restrict__ Wt,
                       const float* __restrict__ bt, short* __restrict__ X2) {
    __shared__ float ls[T2_][65];
    const int bid = blockIdx.x;
    const int b = bid / 20, e0 = (bid % 20) * 64;
    const int tid = threadIdx.x, wave = tid >> 6, lane = tid & 63;
    for (int idx = tid; idx < T2_ * 64; idx += 256) {
        int s = idx >> 6, e = idx & 63;
        ls[s][e] = bf2f(Y[((long)b * T2_ + s) * E_ + e0 + e]);
    }
    __syncthreads();
    for (int t = wave; t < T_; t += 4) {
        const float* wr = Wt + t * T2_;   // wave-uniform -> scalar loads
        float a = 0.f;
        for (int s = 0; s < T2_; ++s) a = fmaf(wr[s], ls[s][lane], a);
        a = gelu_tanh(a + bt[t]);
        X2[((long)b * T_ + t) * E_ + e0 + lane] = f2bf(a);
    }
}

// ---------------- token mixer 2 + residual: S = attn_self + (zt2 mix of X3) ----------
__global__ void ztmix2(const short* __restrict__ X3, const float* __restrict__ Wt,
                       const float* __restrict__ bt, const short* __restrict__ Cat,
                       short* __restrict__ S) {
    __shared__ float ls[T_][65];
    const int bid = blockIdx.x;
    const int b = bid / 20, e0 = (bid % 20) * 64;
    const int tid = threadIdx.x, wave = tid >> 6, lane = tid & 63;
    for (int idx = tid; idx < T_ * 64; idx += 256) {
        int s = idx >> 6, e = idx & 63;
        ls[s][e] = bf2f(X3[((long)b * T_ + s) * E_ + e0 + e]);
    }
    __syncthreads();
    for (int t = wave; t < T_; t += 4) {
        const float* wr = Wt + t * T_;
        float a = 0.f;
        for (int s = 0; s < T_; ++s) a = fmaf(wr[s], ls[s][lane], a);
        a += bt[t];
        float resid = bf2f(Cat[((long)b * T2_ + T_ + t) * E_ + e0 + lane]);
        S[((long)b * T_ + t) * E_ + e0 + lane] = f2bf(a + resid);
    }
}

extern "C" void kernel_launch(void* const* d_in, const int* in_sizes, int n_in,
                              void* d_out, int out_size, void* d_ws, size_t ws_size,
                              hipStream_t stream) {
    const float* hidden = (const float*)d_in[0];
    const float* embeds = (const float*)d_in[1];
    // d_in[2] causal_mask unused (exactly triu(-1e9) -> applied analytically)
    const float* q_w  = (const float*)d_in[3];  const float* q_b  = (const float*)d_in[4];
    const float* k_w  = (const float*)d_in[5];  const float* k_b  = (const float*)d_in[6];
    const float* v_w  = (const float*)d_in[7];  const float* v_b  = (const float*)d_in[8];
    const float* o_w  = (const float*)d_in[9];  const float* o_b  = (const float*)d_in[10];
    const float* ka_w = (const float*)d_in[11]; const float* ka_b = (const float*)d_in[12];
    const float* va_w = (const float*)d_in[13]; const float* va_b = (const float*)d_in[14];
    const float* zc1_w = (const float*)d_in[15]; const float* zc1_b = (const float*)d_in[16];
    const float* zt1_w = (const float*)d_in[17]; const float* zt1_b = (const float*)d_in[18];
    const float* zc2_w = (const float*)d_in[19]; const float* zc2_b = (const float*)d_in[20];
    const float* zt2_w = (const float*)d_in[21]; const float* zt2_b = (const float*)d_in[22];

    char* ws = (char*)d_ws;
    const size_t WSZ = (size_t)E_ * E_ * 2;      // 3,276,800 B per weight
    const size_t ASZ = (size_t)MTOK * E_ * 2;    // 50,462,720 B per activation
    short* Wq  = (short*)(ws + 0 * WSZ);
    short* Wk  = (short*)(ws + 1 * WSZ);
    short* Wv  = (short*)(ws + 2 * WSZ);
    short* Wka = (short*)(ws + 3 * WSZ);
    short* Wva = (short*)(ws + 4 * WSZ);
    short* Wz1 = (short*)(ws + 5 * WSZ);
    short* Wz2 = (short*)(ws + 6 * WSZ);
    short* Wo  = (short*)(ws + 7 * WSZ);
    char* p = ws + 8 * WSZ;
    short* Ahs  = (short*)p; p += ASZ;
    short* Aemb = (short*)p; p += ASZ;
    short* Qb   = (short*)p; p += ASZ;
    short* Kb   = (short*)p; p += ASZ;
    short* Vb   = (short*)p; p += ASZ;
    short* KAb  = (short*)p; p += ASZ;
    short* VAb  = (short*)p; p += ASZ;
    // aliases (lifetimes disjoint in stream order):
    short* CAT = Ahs;   // (B,2T,E) over Ahs+Aemb   — written after q/k/v/ka/va GEMMs
    short* Y   = KAb;   // (B,2T,E) over KAb+VAb    — written after adapter attn
    short* X2  = Qb;    // written after both attns
    short* X3  = Kb;
    short* S   = Vb;

    if (ws_size < (size_t)(p - ws)) return;   // clean-fail signal: absmax == 2.40625

    // casts
    cast_f32_bf16<<<2048, 256, 0, stream>>>(hidden, Ahs,  MTOK * E_ / 4);
    cast_f32_bf16<<<2048, 256, 0, stream>>>(embeds, Aemb, MTOK * E_ / 4);
    cast_f32_bf16<<<512, 256, 0, stream>>>(q_w,  Wq,  E_ * E_ / 4);
    cast_f32_bf16<<<512, 256, 0, stream>>>(k_w,  Wk,  E_ * E_ / 4);
    cast_f32_bf16<<<512, 256, 0, stream>>>(v_w,  Wv,  E_ * E_ / 4);
    cast_f32_bf16<<<512, 256, 0, stream>>>(ka_w, Wka, E_ * E_ / 4);
    cast_f32_bf16<<<512, 256, 0, stream>>>(va_w, Wva, E_ * E_ / 4);
    cast_f32_bf16<<<512, 256, 0, stream>>>(zc1_w, Wz1, E_ * E_ / 4);
    cast_f32_bf16<<<512, 256, 0, stream>>>(zc2_w, Wz2, E_ * E_ / 4);
    cast_f32_bf16<<<512, 256, 0, stream>>>(o_w,  Wo,  E_ * E_ / 4);

    dim3 g154(MTOK / 128, E_ / 128);    // (154, 10)
    dim3 g308(MTOK2 / 128, E_ / 128);   // (308, 10)
    // projections
    gemm_bt<1><<<g154, 256, 0, stream>>>(Ahs,  Wq,  q_b,  Qb,  E_, 0.125f); // (x@Wq^T+b)*scale
    gemm_bt<0><<<g154, 256, 0, stream>>>(Ahs,  Wk,  k_b,  Kb,  E_, 1.f);
    gemm_bt<0><<<g154, 256, 0, stream>>>(Ahs,  Wv,  v_b,  Vb,  E_, 1.f);
    gemm_bt<0><<<g154, 256, 0, stream>>>(Aemb, Wka, ka_b, KAb, E_, 1.f);
    gemm_bt<0><<<g154, 256, 0, stream>>>(Aemb, Wva, va_b, VAb, E_, 1.f);
    // attention: adapter rows [0,77), self rows [77,154) of CAT
    attn_kernel<true ><<<B_ * H_, 256, 0, stream>>>(Qb, Kb,  Vb,  CAT, T_);
    attn_kernel<false><<<B_ * H_, 256, 0, stream>>>(Qb, KAb, VAb, CAT, 0);
    // zipper
    gemm_bt<2><<<g308, 256, 0, stream>>>(CAT, Wz1, zc1_b, Y, E_, 1.f);      // gelu
    ztmix1<<<B_ * 20, 256, 0, stream>>>(Y, zt1_w, zt1_b, X2);
    gemm_bt<0><<<g154, 256, 0, stream>>>(X2, Wz2, zc2_b, X3, E_, 1.f);
    ztmix2<<<B_ * 20, 256, 0, stream>>>(X3, zt2_w, zt2_b, CAT, S);
    // output projection -> fp32 d_out
    gemm_bt<3><<<g154, 256, 0, stream>>>(S, Wo, o_b, (float*)d_out, E_, 1.f);
}

// Round 5
// 2138.943 us; speedup vs baseline: 1.6402x; 1.6402x over previous
//
#include <hip/hip_runtime.h>
#include <stdint.h>

#define B_    256
#define T_    77
#define E_    1280
#define H_    20
#define T2_   154
#define MTOK  19712   // B_*T_
#define MTOK2 39424   // B_*T2_

typedef float f32x4 __attribute__((ext_vector_type(4)));
typedef short bf16x8 __attribute__((ext_vector_type(8)));

__device__ inline float bf2f(short s) {
    return __uint_as_float(((unsigned)(unsigned short)s) << 16);
}
__device__ inline short f2bf(float f) {
    unsigned u = __float_as_uint(f);
    u += 0x7fff + ((u >> 16) & 1);   // RNE
    return (short)(u >> 16);
}
__device__ inline float gelu_tanh(float x) {   // jax.nn.gelu approximate=True
    float x3 = x * x * x;
    return 0.5f * x * (1.0f + tanhf(0.7978845608028654f * (x + 0.044715f * x3)));
}

// ---------------- fp32 -> bf16 cast ----------------
__global__ void cast_f32_bf16(const float* __restrict__ in, short* __restrict__ out, int n4) {
    int i = blockIdx.x * blockDim.x + threadIdx.x;
    int stride = gridDim.x * blockDim.x;
    for (; i < n4; i += stride) {
        float4 v = reinterpret_cast<const float4*>(in)[i];
        short4 o;
        o.x = f2bf(v.x); o.y = f2bf(v.y); o.z = f2bf(v.z); o.w = f2bf(v.w);
        reinterpret_cast<short4*>(out)[i] = o;
    }
}

// ---------------- pad token-mix weight: fp32 (rows x cols) -> bf16 [80][KP], zero pad ----
__global__ void pad_weight(const float* __restrict__ W, short* __restrict__ Wp,
                           int rows, int cols, int KP) {
    int i = blockIdx.x * 256 + threadIdx.x;
    if (i >= 80 * KP) return;
    int t = i / KP, s = i - t * KP;
    Wp[i] = (t < rows && s < cols) ? f2bf(W[t * cols + s]) : (short)0;
}

// ---------------- bf16 GEMM: C[M,N] = A[M,K] @ W[N,K]^T (+epilogue) -------------
// m97 structure: 128x128 tile, BK=64, 4 waves (each 64x64), global_load_lds w=16.
// EPI: 0 = +bias -> bf16 ; 1 = (+bias)*scale -> bf16 ; 2 = gelu(+bias) -> bf16 ;
//      3 = +bias -> fp32
template<int EPI>
__global__ void gemm_bt(const short* __restrict__ A, const short* __restrict__ W,
                        const float* __restrict__ bias, void* __restrict__ Cout,
                        int K, float scale) {
    const int N = E_;
    __shared__ short Als[128 * 64];
    __shared__ short Bls[128 * 64];
    const int tid  = threadIdx.x;
    const int wave = tid >> 6, lane = tid & 63;
    const int bm = blockIdx.x, bn = blockIdx.y;
    const int wm = (wave >> 1) * 64, wn = (wave & 1) * 64;

    f32x4 acc[4][4] = {};

    const long arow0 = (long)bm * 128;
    const long brow0 = (long)bn * 128;
    const int rsub = lane >> 3;          // 0..7 row within 8-row chunk
    const int col  = (lane & 7) * 8;     // 0..56, 8 bf16 = 16B per lane

    for (int kt = 0; kt < K; kt += 64) {
        __syncthreads();   // prev compute done before overwriting LDS
#pragma unroll
        for (int i = 0; i < 4; ++i) {
            int chunk = i * 4 + wave;          // 0..15, 8 rows each
            int row = chunk * 8 + rsub;
            const short* ga = A + (arow0 + row) * K + kt + col;
            const short* gb = W + (brow0 + row) * K + kt + col;
            __builtin_amdgcn_global_load_lds(
                (const __attribute__((address_space(1))) unsigned int*)ga,
                (__attribute__((address_space(3))) unsigned int*)&Als[chunk * 512], 16, 0, 0);
            __builtin_amdgcn_global_load_lds(
                (const __attribute__((address_space(1))) unsigned int*)gb,
                (__attribute__((address_space(3))) unsigned int*)&Bls[chunk * 512], 16, 0, 0);
        }
        __syncthreads();   // drains vmcnt -> tiles ready
#pragma unroll
        for (int kk = 0; kk < 2; ++kk) {
            bf16x8 af[4], bfr[4];
#pragma unroll
            for (int mi = 0; mi < 4; ++mi)
                af[mi] = *reinterpret_cast<const bf16x8*>(
                    &Als[(wm + mi * 16 + (lane & 15)) * 64 + kk * 32 + (lane >> 4) * 8]);
#pragma unroll
            for (int nj = 0; nj < 4; ++nj)
                bfr[nj] = *reinterpret_cast<const bf16x8*>(
                    &Bls[(wn + nj * 16 + (lane & 15)) * 64 + kk * 32 + (lane >> 4) * 8]);
#pragma unroll
            for (int mi = 0; mi < 4; ++mi)
#pragma unroll
                for (int nj = 0; nj < 4; ++nj)
                    acc[mi][nj] = __builtin_amdgcn_mfma_f32_16x16x32_bf16(
                        af[mi], bfr[nj], acc[mi][nj], 0, 0, 0);
        }
    }

    // epilogue: C/D layout col=lane&15, row=(lane>>4)*4+r  [m89-verified]
#pragma unroll
    for (int mi = 0; mi < 4; ++mi) {
#pragma unroll
        for (int nj = 0; nj < 4; ++nj) {
            int gcol = bn * 128 + wn + nj * 16 + (lane & 15);
            float bv = bias[gcol];
#pragma unroll
            for (int r = 0; r < 4; ++r) {
                long grow = arow0 + wm + mi * 16 + (lane >> 4) * 4 + r;
                float v = acc[mi][nj][r] + bv;
                if (EPI == 1) v *= scale;
                if (EPI == 2) v = gelu_tanh(v);
                if (EPI == 3) ((float*)Cout)[grow * N + gcol] = v;
                else          ((short*)Cout)[grow * N + gcol] = f2bf(v);
            }
        }
    }
}

// ---------------- MFMA token mixer ----------------
// OUT[b,t,e] = epi( sum_s Wp[t][s] * IN[b,s,e] + bias[t] )  (+ residual)
// Wp: bf16 [80][KP], rows>=77 and cols>=SIN zeroed. One block per (e-slice of 64, b).
// LDS holds IN^T for the slice: lsT[e_local][s], padded stride PS.
// K-tail [SIN,KP) is explicitly ZEROED in LDS: weight cols there are zero, but
// 0*garbage could be NaN if stale LDS holds NaN/Inf bit patterns (round-2 bug).
template<int SIN, int KP, int PS, bool GELU, bool RESID>
__global__ void mixer_mfma(const short* __restrict__ IN, const short* __restrict__ Wp,
                           const float* __restrict__ bias, const short* __restrict__ Cat,
                           short* __restrict__ OUT) {
    __shared__ short lsT[64 * PS];
    const int e0 = blockIdx.x * 64;
    const int b  = blockIdx.y;
    const int tid = threadIdx.x, wave = tid >> 6, lane = tid & 63;

    // stage IN[b, s, e0..e0+63] transposed -> lsT[e][s]; zero the [SIN,KP) tail
    const int eg = tid & 7;       // which 8-e group this thread handles
    const int sl = tid >> 3;      // s row, 32 per pass
    for (int sb = sl; sb < KP; sb += 32) {
        if (sb < SIN) {
            bf16x8 v = *reinterpret_cast<const bf16x8*>(
                &IN[((long)b * SIN + sb) * E_ + e0 + eg * 8]);
#pragma unroll
            for (int i = 0; i < 8; ++i)
                lsT[(eg * 8 + i) * PS + sb] = v[i];
        } else {
#pragma unroll
            for (int i = 0; i < 8; ++i)
                lsT[(eg * 8 + i) * PS + sb] = 0;
        }
    }
    __syncthreads();

    const int ebase = wave * 16;          // e-subtile owned by this wave
    f32x4 acc[5] = {};
#pragma unroll
    for (int ks = 0; ks < KP / 32; ++ks) {
        bf16x8 bfr = *reinterpret_cast<const bf16x8*>(
            &lsT[(ebase + (lane & 15)) * PS + ks * 32 + (lane >> 4) * 8]);
#pragma unroll
        for (int mt = 0; mt < 5; ++mt) {
            bf16x8 af = *reinterpret_cast<const bf16x8*>(
                &Wp[(mt * 16 + (lane & 15)) * KP + ks * 32 + (lane >> 4) * 8]);
            acc[mt] = __builtin_amdgcn_mfma_f32_16x16x32_bf16(af, bfr, acc[mt], 0, 0, 0);
        }
    }

    const int e = e0 + ebase + (lane & 15);
#pragma unroll
    for (int mt = 0; mt < 5; ++mt) {
#pragma unroll
        for (int r = 0; r < 4; ++r) {
            int t = mt * 16 + (lane >> 4) * 4 + r;
            if (t < T_) {
                float v = acc[mt][r] + bias[t];
                if (GELU) v = gelu_tanh(v);
                if (RESID) v += bf2f(Cat[((long)b * T2_ + T_ + t) * E_ + e]);
                OUT[((long)b * T_ + t) * E_ + e] = f2bf(v);
            }
        }
    }
}

// ---------------- attention: one block per (b,h) ----------------
template<bool CAUSAL>
__global__ void attn_kernel(const short* __restrict__ Qm, const short* __restrict__ Km,
                            const short* __restrict__ Vm, short* __restrict__ Cat,
                            int rowoff) {
    __shared__ float Kls[T_][65];   // pad 65: conflict-free
    __shared__ float Vls[T_][65];
    __shared__ float qls[4][64];
    __shared__ float pls[4][128];
    const int bh = blockIdx.x;
    const int b = bh / H_, h = bh % H_;
    const int tid = threadIdx.x, wave = tid >> 6, lane = tid & 63;
    const long base = ((long)b * T_) * E_ + h * 64;

    for (int idx = tid; idx < T_ * 64; idx += 256) {
        int s = idx >> 6, d = idx & 63;
        Kls[s][d] = bf2f(Km[base + (long)s * E_ + d]);
        Vls[s][d] = bf2f(Vm[base + (long)s * E_ + d]);
    }
    __syncthreads();

    const int s1 = lane;
    const bool has2 = (lane + 64) < T_;          // lanes 0..12
    const int s2 = has2 ? lane + 64 : 0;

    for (int t = wave; t < T_; t += 4) {
        qls[wave][lane] = bf2f(Qm[base + (long)t * E_ + lane]);
        asm volatile("s_waitcnt lgkmcnt(0)" ::: "memory");
        __builtin_amdgcn_wave_barrier();

        float a0 = 0.f, a1 = 0.f;
#pragma unroll 16
        for (int d = 0; d < 64; ++d) {
            float qd = qls[wave][d];             // broadcast read
            a0 = fmaf(qd, Kls[s1][d], a0);
            a1 = fmaf(qd, Kls[s2][d], a1);
        }
        bool v1 = CAUSAL ? (s1 <= t) : true;
        bool v2 = has2 && (CAUSAL ? ((lane + 64) <= t) : true);
        float m = fmaxf(v1 ? a0 : -3.0e38f, v2 ? a1 : -3.0e38f);
#pragma unroll
        for (int o = 32; o; o >>= 1) m = fmaxf(m, __shfl_xor(m, o));
        float p0 = v1 ? __expf(a0 - m) : 0.f;
        float p1 = v2 ? __expf(a1 - m) : 0.f;
        float sm = p0 + p1;
#pragma unroll
        for (int o = 32; o; o >>= 1) sm += __shfl_xor(sm, o);
        float inv = 1.0f / sm;
        pls[wave][lane] = p0 * inv;
        pls[wave][lane + 64] = p1 * inv;
        asm volatile("s_waitcnt lgkmcnt(0)" ::: "memory");
        __builtin_amdgcn_wave_barrier();

        float o_ = 0.f;
        for (int s = 0; s < T_; ++s)
            o_ = fmaf(pls[wave][s], Vls[s][lane], o_);   // p broadcast, V 2-way (free)

        Cat[((long)b * T2_ + rowoff + t) * E_ + h * 64 + lane] = f2bf(o_);
        __builtin_amdgcn_wave_barrier();
    }
}

extern "C" void kernel_launch(void* const* d_in, const int* in_sizes, int n_in,
                              void* d_out, int out_size, void* d_ws, size_t ws_size,
                              hipStream_t stream) {
    const float* hidden = (const float*)d_in[0];
    const float* embeds = (const float*)d_in[1];
    // d_in[2] causal_mask unused (exactly triu(-1e9) -> applied analytically)
    const float* q_w  = (const float*)d_in[3];  const float* q_b  = (const float*)d_in[4];
    const float* k_w  = (const float*)d_in[5];  const float* k_b  = (const float*)d_in[6];
    const float* v_w  = (const float*)d_in[7];  const float* v_b  = (const float*)d_in[8];
    const float* o_w  = (const float*)d_in[9];  const float* o_b  = (const float*)d_in[10];
    const float* ka_w = (const float*)d_in[11]; const float* ka_b = (const float*)d_in[12];
    const float* va_w = (const float*)d_in[13]; const float* va_b = (const float*)d_in[14];
    const float* zc1_w = (const float*)d_in[15]; const float* zc1_b = (const float*)d_in[16];
    const float* zt1_w = (const float*)d_in[17]; const float* zt1_b = (const float*)d_in[18];
    const float* zc2_w = (const float*)d_in[19]; const float* zc2_b = (const float*)d_in[20];
    const float* zt2_w = (const float*)d_in[21]; const float* zt2_b = (const float*)d_in[22];

    char* ws = (char*)d_ws;
    const size_t WSZ = (size_t)E_ * E_ * 2;      // 3,276,800 B per weight
    const size_t ASZ = (size_t)MTOK * E_ * 2;    // 50,462,720 B per activation
    short* Wq  = (short*)(ws + 0 * WSZ);
    short* Wk  = (short*)(ws + 1 * WSZ);
    short* Wv  = (short*)(ws + 2 * WSZ);
    short* Wka = (short*)(ws + 3 * WSZ);
    short* Wva = (short*)(ws + 4 * WSZ);
    short* Wz1 = (short*)(ws + 5 * WSZ);
    short* Wz2 = (short*)(ws + 6 * WSZ);
    short* Wo  = (short*)(ws + 7 * WSZ);
    char* p = ws + 8 * WSZ;
    short* Ahs  = (short*)p; p += ASZ;
    short* Aemb = (short*)p; p += ASZ;
    short* Qb   = (short*)p; p += ASZ;
    short* Kb   = (short*)p; p += ASZ;
    short* Vb   = (short*)p; p += ASZ;
    short* KAb  = (short*)p; p += ASZ;
    short* VAb  = (short*)p; p += ASZ;
    short* Wz1p = (short*)p; p += 80 * 160 * 2;  // padded zt1_w bf16 [80][160]
    short* Wz2p = (short*)p; p += 80 * 96 * 2;   // padded zt2_w bf16 [80][96]
    // aliases (lifetimes disjoint in stream order):
    short* CAT = Ahs;   // (B,2T,E) over Ahs+Aemb   — written after q/k/v/ka/va GEMMs
    short* Y   = KAb;   // (B,2T,E) over KAb+VAb    — written after adapter attn
    short* X2  = Qb;    // written after both attns
    short* X3  = Kb;
    short* S   = Vb;

    if (ws_size < (size_t)(p - ws)) return;   // clean-fail signal

    // casts
    cast_f32_bf16<<<2048, 256, 0, stream>>>(hidden, Ahs,  MTOK * E_ / 4);
    cast_f32_bf16<<<2048, 256, 0, stream>>>(embeds, Aemb, MTOK * E_ / 4);
    cast_f32_bf16<<<512, 256, 0, stream>>>(q_w,  Wq,  E_ * E_ / 4);
    cast_f32_bf16<<<512, 256, 0, stream>>>(k_w,  Wk,  E_ * E_ / 4);
    cast_f32_bf16<<<512, 256, 0, stream>>>(v_w,  Wv,  E_ * E_ / 4);
    cast_f32_bf16<<<512, 256, 0, stream>>>(ka_w, Wka, E_ * E_ / 4);
    cast_f32_bf16<<<512, 256, 0, stream>>>(va_w, Wva, E_ * E_ / 4);
    cast_f32_bf16<<<512, 256, 0, stream>>>(zc1_w, Wz1, E_ * E_ / 4);
    cast_f32_bf16<<<512, 256, 0, stream>>>(zc2_w, Wz2, E_ * E_ / 4);
    cast_f32_bf16<<<512, 256, 0, stream>>>(o_w,  Wo,  E_ * E_ / 4);
    pad_weight<<<(80 * 160 + 255) / 256, 256, 0, stream>>>(zt1_w, Wz1p, 77, 154, 160);
    pad_weight<<<(80 * 96 + 255) / 256, 256, 0, stream>>>(zt2_w, Wz2p, 77, 77, 96);

    dim3 g154(MTOK / 128, E_ / 128);    // (154, 10)
    dim3 g308(MTOK2 / 128, E_ / 128);   // (308, 10)
    // projections
    gemm_bt<1><<<g154, 256, 0, stream>>>(Ahs,  Wq,  q_b,  Qb,  E_, 0.125f); // (x@Wq^T+b)*scale
    gemm_bt<0><<<g154, 256, 0, stream>>>(Ahs,  Wk,  k_b,  Kb,  E_, 1.f);
    gemm_bt<0><<<g154, 256, 0, stream>>>(Ahs,  Wv,  v_b,  Vb,  E_, 1.f);
    gemm_bt<0><<<g154, 256, 0, stream>>>(Aemb, Wka, ka_b, KAb, E_, 1.f);
    gemm_bt<0><<<g154, 256, 0, stream>>>(Aemb, Wva, va_b, VAb, E_, 1.f);
    // attention: adapter rows [0,77), self rows [77,154) of CAT
    attn_kernel<true ><<<B_ * H_, 256, 0, stream>>>(Qb, Kb,  Vb,  CAT, T_);
    attn_kernel<false><<<B_ * H_, 256, 0, stream>>>(Qb, KAb, VAb, CAT, 0);
    // zipper
    gemm_bt<2><<<g308, 256, 0, stream>>>(CAT, Wz1, zc1_b, Y, E_, 1.f);      // gelu
    mixer_mfma<154, 160, 168, true, false><<<dim3(E_ / 64, B_), 256, 0, stream>>>(
        Y, Wz1p, zt1_b, nullptr, X2);
    gemm_bt<0><<<g154, 256, 0, stream>>>(X2, Wz2, zc2_b, X3, E_, 1.f);
    mixer_mfma<77, 96, 104, false, true><<<dim3(E_ / 64, B_), 256, 0, stream>>>(
        X3, Wz2p, zt2_b, CAT, S);
    // output projection -> fp32 d_out
    gemm_bt<3><<<g154, 256, 0, stream>>>(S, Wo, o_b, (float*)d_out, E_, 1.f);
}

// Round 6
// 1187.333 us; speedup vs baseline: 2.9547x; 1.8015x over previous
//
#include <hip/hip_runtime.h>
#include <stdint.h>

#define B_    256
#define T_    77
#define E_    1280
#define H_    20
#define T2_   154
#define MTOK  19712   // B_*T_
#define MTOK2 39424   // B_*T2_

typedef float f32x4 __attribute__((ext_vector_type(4)));
typedef short bf16x8 __attribute__((ext_vector_type(8)));

__device__ inline float bf2f(short s) {
    return __uint_as_float(((unsigned)(unsigned short)s) << 16);
}
__device__ inline short f2bf(float f) {
    unsigned u = __float_as_uint(f);
    u += 0x7fff + ((u >> 16) & 1);   // RNE
    return (short)(u >> 16);
}
__device__ inline float gelu_tanh(float x) {   // jax.nn.gelu approximate=True
    float x3 = x * x * x;
    return 0.5f * x * (1.0f + tanhf(0.7978845608028654f * (x + 0.044715f * x3)));
}

// ---------------- fp32 -> bf16 cast ----------------
__global__ void cast_f32_bf16(const float* __restrict__ in, short* __restrict__ out, int n4) {
    int i = blockIdx.x * blockDim.x + threadIdx.x;
    int stride = gridDim.x * blockDim.x;
    for (; i < n4; i += stride) {
        float4 v = reinterpret_cast<const float4*>(in)[i];
        short4 o;
        o.x = f2bf(v.x); o.y = f2bf(v.y); o.z = f2bf(v.z); o.w = f2bf(v.w);
        reinterpret_cast<short4*>(out)[i] = o;
    }
}

// ---------------- pad token-mix weight: fp32 (rows x cols) -> bf16 [80][KP], zero pad ----
__global__ void pad_weight(const float* __restrict__ W, short* __restrict__ Wp,
                           int rows, int cols, int KP) {
    int i = blockIdx.x * 256 + threadIdx.x;
    if (i >= 80 * KP) return;
    int t = i / KP, s = i - t * KP;
    Wp[i] = (t < rows && s < cols) ? f2bf(W[t * cols + s]) : (short)0;
}

// ---------------- bf16 GEMM: C[M,N] = A[M,K] @ W[N,K]^T (+epilogue) -------------
// m97 structure: 128x128 tile, BK=64, 4 waves (each 64x64), global_load_lds w=16.
// EPI: 0 = +bias -> bf16 ; 1 = (+bias)*scale -> bf16 ; 2 = gelu(+bias) -> bf16 ;
//      3 = +bias -> fp32
template<int EPI>
__global__ void gemm_bt(const short* __restrict__ A, const short* __restrict__ W,
                        const float* __restrict__ bias, void* __restrict__ Cout,
                        int K, float scale) {
    const int N = E_;
    __shared__ short Als[128 * 64];
    __shared__ short Bls[128 * 64];
    const int tid  = threadIdx.x;
    const int wave = tid >> 6, lane = tid & 63;
    const int bm = blockIdx.x, bn = blockIdx.y;
    const int wm = (wave >> 1) * 64, wn = (wave & 1) * 64;

    f32x4 acc[4][4] = {};

    const long arow0 = (long)bm * 128;
    const long brow0 = (long)bn * 128;
    const int rsub = lane >> 3;          // 0..7 row within 8-row chunk
    const int col  = (lane & 7) * 8;     // 0..56, 8 bf16 = 16B per lane

    for (int kt = 0; kt < K; kt += 64) {
        __syncthreads();   // prev compute done before overwriting LDS
#pragma unroll
        for (int i = 0; i < 4; ++i) {
            int chunk = i * 4 + wave;          // 0..15, 8 rows each
            int row = chunk * 8 + rsub;
            const short* ga = A + (arow0 + row) * K + kt + col;
            const short* gb = W + (brow0 + row) * K + kt + col;
            __builtin_amdgcn_global_load_lds(
                (const __attribute__((address_space(1))) unsigned int*)ga,
                (__attribute__((address_space(3))) unsigned int*)&Als[chunk * 512], 16, 0, 0);
            __builtin_amdgcn_global_load_lds(
                (const __attribute__((address_space(1))) unsigned int*)gb,
                (__attribute__((address_space(3))) unsigned int*)&Bls[chunk * 512], 16, 0, 0);
        }
        __syncthreads();   // drains vmcnt -> tiles ready
#pragma unroll
        for (int kk = 0; kk < 2; ++kk) {
            bf16x8 af[4], bfr[4];
#pragma unroll
            for (int mi = 0; mi < 4; ++mi)
                af[mi] = *reinterpret_cast<const bf16x8*>(
                    &Als[(wm + mi * 16 + (lane & 15)) * 64 + kk * 32 + (lane >> 4) * 8]);
#pragma unroll
            for (int nj = 0; nj < 4; ++nj)
                bfr[nj] = *reinterpret_cast<const bf16x8*>(
                    &Bls[(wn + nj * 16 + (lane & 15)) * 64 + kk * 32 + (lane >> 4) * 8]);
#pragma unroll
            for (int mi = 0; mi < 4; ++mi)
#pragma unroll
                for (int nj = 0; nj < 4; ++nj)
                    acc[mi][nj] = __builtin_amdgcn_mfma_f32_16x16x32_bf16(
                        af[mi], bfr[nj], acc[mi][nj], 0, 0, 0);
        }
    }

    // epilogue: C/D layout col=lane&15, row=(lane>>4)*4+r  [m89-verified]
#pragma unroll
    for (int mi = 0; mi < 4; ++mi) {
#pragma unroll
        for (int nj = 0; nj < 4; ++nj) {
            int gcol = bn * 128 + wn + nj * 16 + (lane & 15);
            float bv = bias[gcol];
#pragma unroll
            for (int r = 0; r < 4; ++r) {
                long grow = arow0 + wm + mi * 16 + (lane >> 4) * 4 + r;
                float v = acc[mi][nj][r] + bv;
                if (EPI == 1) v *= scale;
                if (EPI == 2) v = gelu_tanh(v);
                if (EPI == 3) ((float*)Cout)[grow * N + gcol] = v;
                else          ((short*)Cout)[grow * N + gcol] = f2bf(v);
            }
        }
    }
}

// ---------------- MFMA token mixer ----------------
template<int SIN, int KP, int PS, bool GELU, bool RESID>
__global__ void mixer_mfma(const short* __restrict__ IN, const short* __restrict__ Wp,
                           const float* __restrict__ bias, const short* __restrict__ Cat,
                           short* __restrict__ OUT) {
    __shared__ short lsT[64 * PS];
    const int e0 = blockIdx.x * 64;
    const int b  = blockIdx.y;
    const int tid = threadIdx.x, wave = tid >> 6, lane = tid & 63;

    const int eg = tid & 7;       // which 8-e group this thread handles
    const int sl = tid >> 3;      // s row, 32 per pass
    for (int sb = sl; sb < KP; sb += 32) {
        if (sb < SIN) {
            bf16x8 v = *reinterpret_cast<const bf16x8*>(
                &IN[((long)b * SIN + sb) * E_ + e0 + eg * 8]);
#pragma unroll
            for (int i = 0; i < 8; ++i)
                lsT[(eg * 8 + i) * PS + sb] = v[i];
        } else {
#pragma unroll
            for (int i = 0; i < 8; ++i)
                lsT[(eg * 8 + i) * PS + sb] = 0;
        }
    }
    __syncthreads();

    const int ebase = wave * 16;          // e-subtile owned by this wave
    f32x4 acc[5] = {};
#pragma unroll
    for (int ks = 0; ks < KP / 32; ++ks) {
        bf16x8 bfr = *reinterpret_cast<const bf16x8*>(
            &lsT[(ebase + (lane & 15)) * PS + ks * 32 + (lane >> 4) * 8]);
#pragma unroll
        for (int mt = 0; mt < 5; ++mt) {
            bf16x8 af = *reinterpret_cast<const bf16x8*>(
                &Wp[(mt * 16 + (lane & 15)) * KP + ks * 32 + (lane >> 4) * 8]);
            acc[mt] = __builtin_amdgcn_mfma_f32_16x16x32_bf16(af, bfr, acc[mt], 0, 0, 0);
        }
    }

    const int e = e0 + ebase + (lane & 15);
#pragma unroll
    for (int mt = 0; mt < 5; ++mt) {
#pragma unroll
        for (int r = 0; r < 4; ++r) {
            int t = mt * 16 + (lane >> 4) * 4 + r;
            if (t < T_) {
                float v = acc[mt][r] + bias[t];
                if (GELU) v = gelu_tanh(v);
                if (RESID) v += bf2f(Cat[((long)b * T2_ + T_ + t) * E_ + e]);
                OUT[((long)b * T_ + t) * E_ + e] = f2bf(v);
            }
        }
    }
}

// ---------------- fused MFMA attention: one WAVE per (b,h), both passes ----------------
// Pass 0: self-attn (K,V, causal) -> CAT rows [T_, 2T_)
// Pass 1: adapter   (KA,VA)       -> CAT rows [0, T_)
// S = Q.K^T via mfma 16x16x32 (frags straight from global, rows clamped to 76);
// masked softmax in C-layout (shfl_xor over 16-lane group), unnormalized P -> LDS;
// V^T staged to LDS (lane = s => conflict-free transpose writes); PV via mfma;
// 1/rowsum applied in epilogue. K padded to 96 with LDS tails explicitly zeroed.
#define ASTR 104   // LDS row stride (shorts): 16B-aligned, <=2-way banks on b128
__global__ __launch_bounds__(64, 1)
void attn_mfma(const short* __restrict__ Qm,
               const short* __restrict__ Km, const short* __restrict__ Vm,
               const short* __restrict__ KAm, const short* __restrict__ VAm,
               short* __restrict__ Cat) {
    __shared__ short pls[80 * ASTR];
    __shared__ short vt[64 * ASTR];
    const int hh = blockIdx.x;
    const int b = hh / H_, h = hh % H_;
    const int lane = threadIdx.x & 63;
    const int colbase = lane & 15, g = lane >> 4;
    const long base = ((long)b * T_) * E_ + h * 64;

    for (int pass = 0; pass < 2; ++pass) {
        const short* Kp = pass ? KAm : Km;
        const short* Vp = pass ? VAm : Vm;
        const bool causal = (pass == 0);
        const int rowoff = pass ? 0 : T_;

        // ---- zero LDS K-tails (cols >= valid range) BEFORE staging ----
        {
            int4 z = {0, 0, 0, 0};
#pragma unroll
            for (int it = 0; it < 4; ++it) {          // vt rows 0..63, cols 64..95
                int idx = it * 64 + lane;
                int row = idx >> 2, cb = idx & 3;
                *reinterpret_cast<int4*>(&vt[row * ASTR + 64 + cb * 8]) = z;
            }
#pragma unroll
            for (int it = 0; it < 3; ++it) {          // pls rows 0..79, cols 80..95
                int idx = it * 64 + lane;
                if (idx < 160) {
                    int row = idx >> 1, cb = idx & 1;
                    *reinterpret_cast<int4*>(&pls[row * ASTR + 80 + cb * 8]) = z;
                }
            }
        }

        // ---- stage V^T: vt[d][s] = V[s][d]; lane = s (transpose writes conflict-free) ----
        {
            const short* vb = Vp + base + (long)lane * E_;
#pragma unroll
            for (int dg = 0; dg < 8; ++dg) {
                bf16x8 v = *reinterpret_cast<const bf16x8*>(vb + dg * 8);
#pragma unroll
                for (int i = 0; i < 8; ++i) vt[(dg * 8 + i) * ASTR + lane] = v[i];
            }
            if (lane < T_ - 64) {
                const short* vb2 = Vp + base + (long)(64 + lane) * E_;
#pragma unroll
                for (int dg = 0; dg < 8; ++dg) {
                    bf16x8 v = *reinterpret_cast<const bf16x8*>(vb2 + dg * 8);
#pragma unroll
                    for (int i = 0; i < 8; ++i) vt[(dg * 8 + i) * ASTR + 64 + lane] = v[i];
                }
            }
        }

        // ---- S = Q.K^T (frags from global; A/B layout = m89-verified gemm pattern) ----
        f32x4 sacc[5][5] = {};
#pragma unroll
        for (int kk = 0; kk < 2; ++kk) {
            bf16x8 qf[5];
#pragma unroll
            for (int mi = 0; mi < 5; ++mi) {
                int t = mi * 16 + colbase; t = t > 76 ? 76 : t;
                qf[mi] = *reinterpret_cast<const bf16x8*>(
                    Qm + base + (long)t * E_ + kk * 32 + g * 8);
            }
#pragma unroll
            for (int nj = 0; nj < 5; ++nj) {
                int s = nj * 16 + colbase; s = s > 76 ? 76 : s;
                bf16x8 kf = *reinterpret_cast<const bf16x8*>(
                    Kp + base + (long)s * E_ + kk * 32 + g * 8);
#pragma unroll
                for (int mi = 0; mi < 5; ++mi)
                    sacc[mi][nj] = __builtin_amdgcn_mfma_f32_16x16x32_bf16(
                        qf[mi], kf, sacc[mi][nj], 0, 0, 0);
            }
        }

        // ---- masked softmax in C-layout; row-reduce across the 16-lane group ----
        float inv[5][4];
#pragma unroll
        for (int mi = 0; mi < 5; ++mi) {
#pragma unroll
            for (int r = 0; r < 4; ++r) {
                int t = mi * 16 + g * 4 + r;
                float mx = -3.0e38f;
#pragma unroll
                for (int nj = 0; nj < 5; ++nj) {
                    int s = nj * 16 + colbase;
                    bool ok = causal ? (s <= t) : (s < T_);
                    if (ok) mx = fmaxf(mx, sacc[mi][nj][r]);
                }
#pragma unroll
                for (int o = 1; o <= 8; o <<= 1) mx = fmaxf(mx, __shfl_xor(mx, o));
                float sum = 0.f;
#pragma unroll
                for (int nj = 0; nj < 5; ++nj) {
                    int s = nj * 16 + colbase;
                    bool ok = causal ? (s <= t) : (s < T_);
                    float pv = ok ? __expf(sacc[mi][nj][r] - mx) : 0.f;
                    sacc[mi][nj][r] = pv;
                    sum += pv;
                }
#pragma unroll
                for (int o = 1; o <= 8; o <<= 1) sum += __shfl_xor(sum, o);
                inv[mi][r] = 1.0f / sum;
            }
        }

        // ---- write unnormalized P (bf16) to LDS ----
#pragma unroll
        for (int mi = 0; mi < 5; ++mi)
#pragma unroll
            for (int nj = 0; nj < 5; ++nj)
#pragma unroll
                for (int r = 0; r < 4; ++r)
                    pls[(mi * 16 + g * 4 + r) * ASTR + nj * 16 + colbase] =
                        f2bf(sacc[mi][nj][r]);

        // ---- ctx = P.V via mfma (A = P rows, B = V^T rows; K = 96) ----
        f32x4 cacc[5][4] = {};
#pragma unroll
        for (int ks = 0; ks < 3; ++ks) {
            bf16x8 pa[5];
#pragma unroll
            for (int mi = 0; mi < 5; ++mi)
                pa[mi] = *reinterpret_cast<const bf16x8*>(
                    &pls[(mi * 16 + colbase) * ASTR + ks * 32 + g * 8]);
#pragma unroll
            for (int nd = 0; nd < 4; ++nd) {
                bf16x8 vf = *reinterpret_cast<const bf16x8*>(
                    &vt[(nd * 16 + colbase) * ASTR + ks * 32 + g * 8]);
#pragma unroll
                for (int mi = 0; mi < 5; ++mi)
                    cacc[mi][nd] = __builtin_amdgcn_mfma_f32_16x16x32_bf16(
                        pa[mi], vf, cacc[mi][nd], 0, 0, 0);
            }
        }

        // ---- epilogue: normalize by 1/rowsum, write CAT ----
#pragma unroll
        for (int mi = 0; mi < 5; ++mi)
#pragma unroll
            for (int nd = 0; nd < 4; ++nd)
#pragma unroll
                for (int r = 0; r < 4; ++r) {
                    int t = mi * 16 + g * 4 + r;
                    if (t < T_) {
                        float val = cacc[mi][nd][r] * inv[mi][r];
                        Cat[((long)b * T2_ + rowoff + t) * E_ + h * 64 + nd * 16 + colbase] =
                            f2bf(val);
                    }
                }
    }
}

extern "C" void kernel_launch(void* const* d_in, const int* in_sizes, int n_in,
                              void* d_out, int out_size, void* d_ws, size_t ws_size,
                              hipStream_t stream) {
    const float* hidden = (const float*)d_in[0];
    const float* embeds = (const float*)d_in[1];
    // d_in[2] causal_mask unused (exactly triu(-1e9) -> applied analytically)
    const float* q_w  = (const float*)d_in[3];  const float* q_b  = (const float*)d_in[4];
    const float* k_w  = (const float*)d_in[5];  const float* k_b  = (const float*)d_in[6];
    const float* v_w  = (const float*)d_in[7];  const float* v_b  = (const float*)d_in[8];
    const float* o_w  = (const float*)d_in[9];  const float* o_b  = (const float*)d_in[10];
    const float* ka_w = (const float*)d_in[11]; const float* ka_b = (const float*)d_in[12];
    const float* va_w = (const float*)d_in[13]; const float* va_b = (const float*)d_in[14];
    const float* zc1_w = (const float*)d_in[15]; const float* zc1_b = (const float*)d_in[16];
    const float* zt1_w = (const float*)d_in[17]; const float* zt1_b = (const float*)d_in[18];
    const float* zc2_w = (const float*)d_in[19]; const float* zc2_b = (const float*)d_in[20];
    const float* zt2_w = (const float*)d_in[21]; const float* zt2_b = (const float*)d_in[22];

    char* ws = (char*)d_ws;
    const size_t WSZ = (size_t)E_ * E_ * 2;      // 3,276,800 B per weight
    const size_t ASZ = (size_t)MTOK * E_ * 2;    // 50,462,720 B per activation
    short* Wq  = (short*)(ws + 0 * WSZ);
    short* Wk  = (short*)(ws + 1 * WSZ);
    short* Wv  = (short*)(ws + 2 * WSZ);
    short* Wka = (short*)(ws + 3 * WSZ);
    short* Wva = (short*)(ws + 4 * WSZ);
    short* Wz1 = (short*)(ws + 5 * WSZ);
    short* Wz2 = (short*)(ws + 6 * WSZ);
    short* Wo  = (short*)(ws + 7 * WSZ);
    char* p = ws + 8 * WSZ;
    short* Ahs  = (short*)p; p += ASZ;
    short* Aemb = (short*)p; p += ASZ;
    short* Qb   = (short*)p; p += ASZ;
    short* Kb   = (short*)p; p += ASZ;
    short* Vb   = (short*)p; p += ASZ;
    short* KAb  = (short*)p; p += ASZ;
    short* VAb  = (short*)p; p += ASZ;
    short* Wz1p = (short*)p; p += 80 * 160 * 2;  // padded zt1_w bf16 [80][160]
    short* Wz2p = (short*)p; p += 80 * 96 * 2;   // padded zt2_w bf16 [80][96]
    // aliases (lifetimes disjoint in stream order):
    short* CAT = Ahs;   // (B,2T,E) over Ahs+Aemb   — written after q/k/v/ka/va GEMMs
    short* Y   = KAb;   // (B,2T,E) over KAb+VAb    — written after adapter attn
    short* X2  = Qb;    // written after both attns
    short* X3  = Kb;
    short* S   = Vb;

    if (ws_size < (size_t)(p - ws)) return;   // clean-fail signal

    // casts
    cast_f32_bf16<<<2048, 256, 0, stream>>>(hidden, Ahs,  MTOK * E_ / 4);
    cast_f32_bf16<<<2048, 256, 0, stream>>>(embeds, Aemb, MTOK * E_ / 4);
    cast_f32_bf16<<<512, 256, 0, stream>>>(q_w,  Wq,  E_ * E_ / 4);
    cast_f32_bf16<<<512, 256, 0, stream>>>(k_w,  Wk,  E_ * E_ / 4);
    cast_f32_bf16<<<512, 256, 0, stream>>>(v_w,  Wv,  E_ * E_ / 4);
    cast_f32_bf16<<<512, 256, 0, stream>>>(ka_w, Wka, E_ * E_ / 4);
    cast_f32_bf16<<<512, 256, 0, stream>>>(va_w, Wva, E_ * E_ / 4);
    cast_f32_bf16<<<512, 256, 0, stream>>>(zc1_w, Wz1, E_ * E_ / 4);
    cast_f32_bf16<<<512, 256, 0, stream>>>(zc2_w, Wz2, E_ * E_ / 4);
    cast_f32_bf16<<<512, 256, 0, stream>>>(o_w,  Wo,  E_ * E_ / 4);
    pad_weight<<<(80 * 160 + 255) / 256, 256, 0, stream>>>(zt1_w, Wz1p, 77, 154, 160);
    pad_weight<<<(80 * 96 + 255) / 256, 256, 0, stream>>>(zt2_w, Wz2p, 77, 77, 96);

    dim3 g154(MTOK / 128, E_ / 128);    // (154, 10)
    dim3 g308(MTOK2 / 128, E_ / 128);   // (308, 10)
    // projections
    gemm_bt<1><<<g154, 256, 0, stream>>>(Ahs,  Wq,  q_b,  Qb,  E_, 0.125f); // (x@Wq^T+b)*scale
    gemm_bt<0><<<g154, 256, 0, stream>>>(Ahs,  Wk,  k_b,  Kb,  E_, 1.f);
    gemm_bt<0><<<g154, 256, 0, stream>>>(Ahs,  Wv,  v_b,  Vb,  E_, 1.f);
    gemm_bt<0><<<g154, 256, 0, stream>>>(Aemb, Wka, ka_b, KAb, E_, 1.f);
    gemm_bt<0><<<g154, 256, 0, stream>>>(Aemb, Wva, va_b, VAb, E_, 1.f);
    // fused attention (both passes): adapter rows [0,77), self rows [77,154) of CAT
    attn_mfma<<<B_ * H_, 64, 0, stream>>>(Qb, Kb, Vb, KAb, VAb, CAT);
    // zipper
    gemm_bt<2><<<g308, 256, 0, stream>>>(CAT, Wz1, zc1_b, Y, E_, 1.f);      // gelu
    mixer_mfma<154, 160, 168, true, false><<<dim3(E_ / 64, B_), 256, 0, stream>>>(
        Y, Wz1p, zt1_b, nullptr, X2);
    gemm_bt<0><<<g154, 256, 0, stream>>>(X2, Wz2, zc2_b, X3, E_, 1.f);
    mixer_mfma<77, 96, 104, false, true><<<dim3(E_ / 64, B_), 256, 0, stream>>>(
        X3, Wz2p, zt2_b, CAT, S);
    // output projection -> fp32 d_out
    gemm_bt<3><<<g154, 256, 0, stream>>>(S, Wo, o_b, (float*)d_out, E_, 1.f);
}

// Round 7
// 1168.871 us; speedup vs baseline: 3.0014x; 1.0158x over previous
//
#include <hip/hip_runtime.h>
#include <stdint.h>

#define B_    256
#define T_    77
#define E_    1280
#define H_    20
#define T2_   154
#define MTOK  19712   // B_*T_
#define MTOK2 39424   // B_*T2_

typedef float f32x4 __attribute__((ext_vector_type(4)));
typedef short bf16x8 __attribute__((ext_vector_type(8)));

__device__ inline float bf2f(short s) {
    return __uint_as_float(((unsigned)(unsigned short)s) << 16);
}
__device__ inline short f2bf(float f) {
    unsigned u = __float_as_uint(f);
    u += 0x7fff + ((u >> 16) & 1);   // RNE
    return (short)(u >> 16);
}
__device__ inline float gelu_tanh(float x) {   // jax.nn.gelu approximate=True
    float x3 = x * x * x;
    return 0.5f * x * (1.0f + tanhf(0.7978845608028654f * (x + 0.044715f * x3)));
}

// ---------------- fp32 -> bf16 cast ----------------
__global__ void cast_f32_bf16(const float* __restrict__ in, short* __restrict__ out, int n4) {
    int i = blockIdx.x * blockDim.x + threadIdx.x;
    int stride = gridDim.x * blockDim.x;
    for (; i < n4; i += stride) {
        float4 v = reinterpret_cast<const float4*>(in)[i];
        short4 o;
        o.x = f2bf(v.x); o.y = f2bf(v.y); o.z = f2bf(v.z); o.w = f2bf(v.w);
        reinterpret_cast<short4*>(out)[i] = o;
    }
}

// ---------------- pad token-mix weight: fp32 (rows x cols) -> bf16 [80][KP], zero pad ----
__global__ void pad_weight(const float* __restrict__ W, short* __restrict__ Wp,
                           int rows, int cols, int KP) {
    int i = blockIdx.x * 256 + threadIdx.x;
    if (i >= 80 * KP) return;
    int t = i / KP, s = i - t * KP;
    Wp[i] = (t < rows && s < cols) ? f2bf(W[t * cols + s]) : (short)0;
}

// ---------------- bf16 GEMM: C[M,N] = A[M,K] @ W[N,K]^T (+epilogue) -------------
// m97 structure: 128x128 tile, BK=64, 4 waves (each 64x64), global_load_lds w=16.
// Grid: (bn=N/128 FAST, bm=M/128) so the 10 N-tiles sharing one A-row-panel run
// back-to-back -> A fetched ~once (L2/LIC), W stays LIC-resident. (R6 fix: the
// old (bm fast, bn slow) order re-fetched all of A per bn: 453 MB/dispatch.)
// EPI: 0 = +bias -> bf16 ; 1 = (+bias)*scale -> bf16 ; 2 = gelu(+bias) -> bf16 ;
//      3 = +bias -> fp32
template<int EPI>
__global__ void gemm_bt(const short* __restrict__ A, const short* __restrict__ W,
                        const float* __restrict__ bias, void* __restrict__ Cout,
                        int K, float scale) {
    const int N = E_;
    __shared__ short Als[128 * 64];
    __shared__ short Bls[128 * 64];
    const int tid  = threadIdx.x;
    const int wave = tid >> 6, lane = tid & 63;
    const int bn = blockIdx.x, bm = blockIdx.y;   // bn fast
    const int wm = (wave >> 1) * 64, wn = (wave & 1) * 64;

    f32x4 acc[4][4] = {};

    const long arow0 = (long)bm * 128;
    const long brow0 = (long)bn * 128;
    const int rsub = lane >> 3;          // 0..7 row within 8-row chunk
    const int col  = (lane & 7) * 8;     // 0..56, 8 bf16 = 16B per lane

    for (int kt = 0; kt < K; kt += 64) {
        __syncthreads();   // prev compute done before overwriting LDS
#pragma unroll
        for (int i = 0; i < 4; ++i) {
            int chunk = i * 4 + wave;          // 0..15, 8 rows each
            int row = chunk * 8 + rsub;
            const short* ga = A + (arow0 + row) * K + kt + col;
            const short* gb = W + (brow0 + row) * K + kt + col;
            __builtin_amdgcn_global_load_lds(
                (const __attribute__((address_space(1))) unsigned int*)ga,
                (__attribute__((address_space(3))) unsigned int*)&Als[chunk * 512], 16, 0, 0);
            __builtin_amdgcn_global_load_lds(
                (const __attribute__((address_space(1))) unsigned int*)gb,
                (__attribute__((address_space(3))) unsigned int*)&Bls[chunk * 512], 16, 0, 0);
        }
        __syncthreads();   // drains vmcnt -> tiles ready
#pragma unroll
        for (int kk = 0; kk < 2; ++kk) {
            bf16x8 af[4], bfr[4];
#pragma unroll
            for (int mi = 0; mi < 4; ++mi)
                af[mi] = *reinterpret_cast<const bf16x8*>(
                    &Als[(wm + mi * 16 + (lane & 15)) * 64 + kk * 32 + (lane >> 4) * 8]);
#pragma unroll
            for (int nj = 0; nj < 4; ++nj)
                bfr[nj] = *reinterpret_cast<const bf16x8*>(
                    &Bls[(wn + nj * 16 + (lane & 15)) * 64 + kk * 32 + (lane >> 4) * 8]);
#pragma unroll
            for (int mi = 0; mi < 4; ++mi)
#pragma unroll
                for (int nj = 0; nj < 4; ++nj)
                    acc[mi][nj] = __builtin_amdgcn_mfma_f32_16x16x32_bf16(
                        af[mi], bfr[nj], acc[mi][nj], 0, 0, 0);
        }
    }

    // epilogue: C/D layout col=lane&15, row=(lane>>4)*4+r  [m89-verified]
#pragma unroll
    for (int mi = 0; mi < 4; ++mi) {
#pragma unroll
        for (int nj = 0; nj < 4; ++nj) {
            int gcol = bn * 128 + wn + nj * 16 + (lane & 15);
            float bv = bias[gcol];
#pragma unroll
            for (int r = 0; r < 4; ++r) {
                long grow = arow0 + wm + mi * 16 + (lane >> 4) * 4 + r;
                float v = acc[mi][nj][r] + bv;
                if (EPI == 1) v *= scale;
                if (EPI == 2) v = gelu_tanh(v);
                if (EPI == 3) ((float*)Cout)[grow * N + gcol] = v;
                else          ((short*)Cout)[grow * N + gcol] = f2bf(v);
            }
        }
    }
}

// ---------------- MFMA token mixer ----------------
template<int SIN, int KP, int PS, bool GELU, bool RESID>
__global__ void mixer_mfma(const short* __restrict__ IN, const short* __restrict__ Wp,
                           const float* __restrict__ bias, const short* __restrict__ Cat,
                           short* __restrict__ OUT) {
    __shared__ short lsT[64 * PS];
    const int e0 = blockIdx.x * 64;
    const int b  = blockIdx.y;
    const int tid = threadIdx.x, wave = tid >> 6, lane = tid & 63;

    const int eg = tid & 7;       // which 8-e group this thread handles
    const int sl = tid >> 3;      // s row, 32 per pass
    for (int sb = sl; sb < KP; sb += 32) {
        if (sb < SIN) {
            bf16x8 v = *reinterpret_cast<const bf16x8*>(
                &IN[((long)b * SIN + sb) * E_ + e0 + eg * 8]);
#pragma unroll
            for (int i = 0; i < 8; ++i)
                lsT[(eg * 8 + i) * PS + sb] = v[i];
        } else {
#pragma unroll
            for (int i = 0; i < 8; ++i)
                lsT[(eg * 8 + i) * PS + sb] = 0;
        }
    }
    __syncthreads();

    const int ebase = wave * 16;          // e-subtile owned by this wave
    f32x4 acc[5] = {};
#pragma unroll
    for (int ks = 0; ks < KP / 32; ++ks) {
        bf16x8 bfr = *reinterpret_cast<const bf16x8*>(
            &lsT[(ebase + (lane & 15)) * PS + ks * 32 + (lane >> 4) * 8]);
#pragma unroll
        for (int mt = 0; mt < 5; ++mt) {
            bf16x8 af = *reinterpret_cast<const bf16x8*>(
                &Wp[(mt * 16 + (lane & 15)) * KP + ks * 32 + (lane >> 4) * 8]);
            acc[mt] = __builtin_amdgcn_mfma_f32_16x16x32_bf16(af, bfr, acc[mt], 0, 0, 0);
        }
    }

    const int e = e0 + ebase + (lane & 15);
#pragma unroll
    for (int mt = 0; mt < 5; ++mt) {
#pragma unroll
        for (int r = 0; r < 4; ++r) {
            int t = mt * 16 + (lane >> 4) * 4 + r;
            if (t < T_) {
                float v = acc[mt][r] + bias[t];
                if (GELU) v = gelu_tanh(v);
                if (RESID) v += bf2f(Cat[((long)b * T2_ + T_ + t) * E_ + e]);
                OUT[((long)b * T_ + t) * E_ + e] = f2bf(v);
            }
        }
    }
}

// ---------------- fused MFMA attention: one WAVE per (b,h), both passes ----------------
#define ASTR 104   // LDS row stride (shorts): 16B-aligned, <=2-way banks on b128
__global__ __launch_bounds__(64, 1)
void attn_mfma(const short* __restrict__ Qm,
               const short* __restrict__ Km, const short* __restrict__ Vm,
               const short* __restrict__ KAm, const short* __restrict__ VAm,
               short* __restrict__ Cat) {
    __shared__ short pls[80 * ASTR];
    __shared__ short vt[64 * ASTR];
    const int hh = blockIdx.x;
    const int b = hh / H_, h = hh % H_;
    const int lane = threadIdx.x & 63;
    const int colbase = lane & 15, g = lane >> 4;
    const long base = ((long)b * T_) * E_ + h * 64;

    for (int pass = 0; pass < 2; ++pass) {
        const short* Kp = pass ? KAm : Km;
        const short* Vp = pass ? VAm : Vm;
        const bool causal = (pass == 0);
        const int rowoff = pass ? 0 : T_;

        // ---- zero LDS K-tails (cols >= valid range) BEFORE staging ----
        {
            int4 z = {0, 0, 0, 0};
#pragma unroll
            for (int it = 0; it < 4; ++it) {          // vt rows 0..63, cols 64..95
                int idx = it * 64 + lane;
                int row = idx >> 2, cb = idx & 3;
                *reinterpret_cast<int4*>(&vt[row * ASTR + 64 + cb * 8]) = z;
            }
#pragma unroll
            for (int it = 0; it < 3; ++it) {          // pls rows 0..79, cols 80..95
                int idx = it * 64 + lane;
                if (idx < 160) {
                    int row = idx >> 1, cb = idx & 1;
                    *reinterpret_cast<int4*>(&pls[row * ASTR + 80 + cb * 8]) = z;
                }
            }
        }

        // ---- stage V^T: vt[d][s] = V[s][d]; lane = s (transpose writes conflict-free) ----
        {
            const short* vb = Vp + base + (long)lane * E_;
#pragma unroll
            for (int dg = 0; dg < 8; ++dg) {
                bf16x8 v = *reinterpret_cast<const bf16x8*>(vb + dg * 8);
#pragma unroll
                for (int i = 0; i < 8; ++i) vt[(dg * 8 + i) * ASTR + lane] = v[i];
            }
            if (lane < T_ - 64) {
                const short* vb2 = Vp + base + (long)(64 + lane) * E_;
#pragma unroll
                for (int dg = 0; dg < 8; ++dg) {
                    bf16x8 v = *reinterpret_cast<const bf16x8*>(vb2 + dg * 8);
#pragma unroll
                    for (int i = 0; i < 8; ++i) vt[(dg * 8 + i) * ASTR + 64 + lane] = v[i];
                }
            }
        }

        // ---- S = Q.K^T (frags from global; A/B layout = m89-verified gemm pattern) ----
        f32x4 sacc[5][5] = {};
#pragma unroll
        for (int kk = 0; kk < 2; ++kk) {
            bf16x8 qf[5];
#pragma unroll
            for (int mi = 0; mi < 5; ++mi) {
                int t = mi * 16 + colbase; t = t > 76 ? 76 : t;
                qf[mi] = *reinterpret_cast<const bf16x8*>(
                    Qm + base + (long)t * E_ + kk * 32 + g * 8);
            }
#pragma unroll
            for (int nj = 0; nj < 5; ++nj) {
                int s = nj * 16 + colbase; s = s > 76 ? 76 : s;
                bf16x8 kf = *reinterpret_cast<const bf16x8*>(
                    Kp + base + (long)s * E_ + kk * 32 + g * 8);
#pragma unroll
                for (int mi = 0; mi < 5; ++mi)
                    sacc[mi][nj] = __builtin_amdgcn_mfma_f32_16x16x32_bf16(
                        qf[mi], kf, sacc[mi][nj], 0, 0, 0);
            }
        }

        // ---- masked softmax in C-layout; row-reduce across the 16-lane group ----
        float inv[5][4];
#pragma unroll
        for (int mi = 0; mi < 5; ++mi) {
#pragma unroll
            for (int r = 0; r < 4; ++r) {
                int t = mi * 16 + g * 4 + r;
                float mx = -3.0e38f;
#pragma unroll
                for (int nj = 0; nj < 5; ++nj) {
                    int s = nj * 16 + colbase;
                    bool ok = causal ? (s <= t) : (s < T_);
                    if (ok) mx = fmaxf(mx, sacc[mi][nj][r]);
                }
#pragma unroll
                for (int o = 1; o <= 8; o <<= 1) mx = fmaxf(mx, __shfl_xor(mx, o));
                float sum = 0.f;
#pragma unroll
                for (int nj = 0; nj < 5; ++nj) {
                    int s = nj * 16 + colbase;
                    bool ok = causal ? (s <= t) : (s < T_);
                    float pv = ok ? __expf(sacc[mi][nj][r] - mx) : 0.f;
                    sacc[mi][nj][r] = pv;
                    sum += pv;
                }
#pragma unroll
                for (int o = 1; o <= 8; o <<= 1) sum += __shfl_xor(sum, o);
                inv[mi][r] = 1.0f / sum;
            }
        }

        // ---- write unnormalized P (bf16) to LDS ----
#pragma unroll
        for (int mi = 0; mi < 5; ++mi)
#pragma unroll
            for (int nj = 0; nj < 5; ++nj)
#pragma unroll
                for (int r = 0; r < 4; ++r)
                    pls[(mi * 16 + g * 4 + r) * ASTR + nj * 16 + colbase] =
                        f2bf(sacc[mi][nj][r]);

        // ---- ctx = P.V via mfma (A = P rows, B = V^T rows; K = 96) ----
        f32x4 cacc[5][4] = {};
#pragma unroll
        for (int ks = 0; ks < 3; ++ks) {
            bf16x8 pa[5];
#pragma unroll
            for (int mi = 0; mi < 5; ++mi)
                pa[mi] = *reinterpret_cast<const bf16x8*>(
                    &pls[(mi * 16 + colbase) * ASTR + ks * 32 + g * 8]);
#pragma unroll
            for (int nd = 0; nd < 4; ++nd) {
                bf16x8 vf = *reinterpret_cast<const bf16x8*>(
                    &vt[(nd * 16 + colbase) * ASTR + ks * 32 + g * 8]);
#pragma unroll
                for (int mi = 0; mi < 5; ++mi)
                    cacc[mi][nd] = __builtin_amdgcn_mfma_f32_16x16x32_bf16(
                        pa[mi], vf, cacc[mi][nd], 0, 0, 0);
            }
        }

        // ---- epilogue: normalize by 1/rowsum, write CAT ----
#pragma unroll
        for (int mi = 0; mi < 5; ++mi)
#pragma unroll
            for (int nd = 0; nd < 4; ++nd)
#pragma unroll
                for (int r = 0; r < 4; ++r) {
                    int t = mi * 16 + g * 4 + r;
                    if (t < T_) {
                        float val = cacc[mi][nd][r] * inv[mi][r];
                        Cat[((long)b * T2_ + rowoff + t) * E_ + h * 64 + nd * 16 + colbase] =
                            f2bf(val);
                    }
                }
    }
}

extern "C" void kernel_launch(void* const* d_in, const int* in_sizes, int n_in,
                              void* d_out, int out_size, void* d_ws, size_t ws_size,
                              hipStream_t stream) {
    const float* hidden = (const float*)d_in[0];
    const float* embeds = (const float*)d_in[1];
    // d_in[2] causal_mask unused (exactly triu(-1e9) -> applied analytically)
    const float* q_w  = (const float*)d_in[3];  const float* q_b  = (const float*)d_in[4];
    const float* k_w  = (const float*)d_in[5];  const float* k_b  = (const float*)d_in[6];
    const float* v_w  = (const float*)d_in[7];  const float* v_b  = (const float*)d_in[8];
    const float* o_w  = (const float*)d_in[9];  const float* o_b  = (const float*)d_in[10];
    const float* ka_w = (const float*)d_in[11]; const float* ka_b = (const float*)d_in[12];
    const float* va_w = (const float*)d_in[13]; const float* va_b = (const float*)d_in[14];
    const float* zc1_w = (const float*)d_in[15]; const float* zc1_b = (const float*)d_in[16];
    const float* zt1_w = (const float*)d_in[17]; const float* zt1_b = (const float*)d_in[18];
    const float* zc2_w = (const float*)d_in[19]; const float* zc2_b = (const float*)d_in[20];
    const float* zt2_w = (const float*)d_in[21]; const float* zt2_b = (const float*)d_in[22];

    char* ws = (char*)d_ws;
    const size_t WSZ = (size_t)E_ * E_ * 2;      // 3,276,800 B per weight
    const size_t ASZ = (size_t)MTOK * E_ * 2;    // 50,462,720 B per activation
    short* Wq  = (short*)(ws + 0 * WSZ);
    short* Wk  = (short*)(ws + 1 * WSZ);
    short* Wv  = (short*)(ws + 2 * WSZ);
    short* Wka = (short*)(ws + 3 * WSZ);
    short* Wva = (short*)(ws + 4 * WSZ);
    short* Wz1 = (short*)(ws + 5 * WSZ);
    short* Wz2 = (short*)(ws + 6 * WSZ);
    short* Wo  = (short*)(ws + 7 * WSZ);
    char* p = ws + 8 * WSZ;
    short* Ahs  = (short*)p; p += ASZ;
    short* Aemb = (short*)p; p += ASZ;
    short* Qb   = (short*)p; p += ASZ;
    short* Kb   = (short*)p; p += ASZ;
    short* Vb   = (short*)p; p += ASZ;
    short* KAb  = (short*)p; p += ASZ;
    short* VAb  = (short*)p; p += ASZ;
    short* Wz1p = (short*)p; p += 80 * 160 * 2;  // padded zt1_w bf16 [80][160]
    short* Wz2p = (short*)p; p += 80 * 96 * 2;   // padded zt2_w bf16 [80][96]
    // aliases (lifetimes disjoint in stream order):
    short* CAT = Ahs;   // (B,2T,E) over Ahs+Aemb   — written after q/k/v/ka/va GEMMs
    short* Y   = KAb;   // (B,2T,E) over KAb+VAb    — written after adapter attn
    short* X2  = Qb;    // written after both attns
    short* X3  = Kb;
    short* S   = Vb;

    if (ws_size < (size_t)(p - ws)) return;   // clean-fail signal

    // casts
    cast_f32_bf16<<<2048, 256, 0, stream>>>(hidden, Ahs,  MTOK * E_ / 4);
    cast_f32_bf16<<<2048, 256, 0, stream>>>(embeds, Aemb, MTOK * E_ / 4);
    cast_f32_bf16<<<512, 256, 0, stream>>>(q_w,  Wq,  E_ * E_ / 4);
    cast_f32_bf16<<<512, 256, 0, stream>>>(k_w,  Wk,  E_ * E_ / 4);
    cast_f32_bf16<<<512, 256, 0, stream>>>(v_w,  Wv,  E_ * E_ / 4);
    cast_f32_bf16<<<512, 256, 0, stream>>>(ka_w, Wka, E_ * E_ / 4);
    cast_f32_bf16<<<512, 256, 0, stream>>>(va_w, Wva, E_ * E_ / 4);
    cast_f32_bf16<<<512, 256, 0, stream>>>(zc1_w, Wz1, E_ * E_ / 4);
    cast_f32_bf16<<<512, 256, 0, stream>>>(zc2_w, Wz2, E_ * E_ / 4);
    cast_f32_bf16<<<512, 256, 0, stream>>>(o_w,  Wo,  E_ * E_ / 4);
    pad_weight<<<(80 * 160 + 255) / 256, 256, 0, stream>>>(zt1_w, Wz1p, 77, 154, 160);
    pad_weight<<<(80 * 96 + 255) / 256, 256, 0, stream>>>(zt2_w, Wz2p, 77, 77, 96);

    dim3 g154(E_ / 128, MTOK / 128);    // (10 fast, 154)  — A-panel reuse
    dim3 g308(E_ / 128, MTOK2 / 128);   // (10 fast, 308)
    // projections
    gemm_bt<1><<<g154, 256, 0, stream>>>(Ahs,  Wq,  q_b,  Qb,  E_, 0.125f); // (x@Wq^T+b)*scale
    gemm_bt<0><<<g154, 256, 0, stream>>>(Ahs,  Wk,  k_b,  Kb,  E_, 1.f);
    gemm_bt<0><<<g154, 256, 0, stream>>>(Ahs,  Wv,  v_b,  Vb,  E_, 1.f);
    gemm_bt<0><<<g154, 256, 0, stream>>>(Aemb, Wka, ka_b, KAb, E_, 1.f);
    gemm_bt<0><<<g154, 256, 0, stream>>>(Aemb, Wva, va_b, VAb, E_, 1.f);
    // fused attention (both passes): adapter rows [0,77), self rows [77,154) of CAT
    attn_mfma<<<B_ * H_, 64, 0, stream>>>(Qb, Kb, Vb, KAb, VAb, CAT);
    // zipper
    gemm_bt<2><<<g308, 256, 0, stream>>>(CAT, Wz1, zc1_b, Y, E_, 1.f);      // gelu
    mixer_mfma<154, 160, 168, true, false><<<dim3(E_ / 64, B_), 256, 0, stream>>>(
        Y, Wz1p, zt1_b, nullptr, X2);
    gemm_bt<0><<<g154, 256, 0, stream>>>(X2, Wz2, zc2_b, X3, E_, 1.f);
    mixer_mfma<77, 96, 104, false, true><<<dim3(E_ / 64, B_), 256, 0, stream>>>(
        X3, Wz2p, zt2_b, CAT, S);
    // output projection -> fp32 d_out
    gemm_bt<3><<<g154, 256, 0, stream>>>(S, Wo, o_b, (float*)d_out, E_, 1.f);
}

// Round 8
// 1129.380 us; speedup vs baseline: 3.1063x; 1.0350x over previous
//
#include <hip/hip_runtime.h>
#include <stdint.h>

#define B_    256
#define T_    77
#define E_    1280
#define H_    20
#define T2_   154
#define MTOK  19712   // B_*T_
#define MTOK2 39424   // B_*T2_

typedef float f32x4 __attribute__((ext_vector_type(4)));
typedef short bf16x8 __attribute__((ext_vector_type(8)));

__device__ inline float bf2f(short s) {
    return __uint_as_float(((unsigned)(unsigned short)s) << 16);
}
__device__ inline short f2bf(float f) {
    unsigned u = __float_as_uint(f);
    u += 0x7fff + ((u >> 16) & 1);   // RNE
    return (short)(u >> 16);
}
__device__ inline float gelu_tanh(float x) {   // jax.nn.gelu approximate=True
    float x3 = x * x * x;
    return 0.5f * x * (1.0f + tanhf(0.7978845608028654f * (x + 0.044715f * x3)));
}

// ---------------- fp32 -> bf16 cast ----------------
__global__ void cast_f32_bf16(const float* __restrict__ in, short* __restrict__ out, int n4) {
    int i = blockIdx.x * blockDim.x + threadIdx.x;
    int stride = gridDim.x * blockDim.x;
    for (; i < n4; i += stride) {
        float4 v = reinterpret_cast<const float4*>(in)[i];
        short4 o;
        o.x = f2bf(v.x); o.y = f2bf(v.y); o.z = f2bf(v.z); o.w = f2bf(v.w);
        reinterpret_cast<short4*>(out)[i] = o;
    }
}

// ---------------- pad token-mix weight: fp32 (rows x cols) -> bf16 [80][KP], zero pad ----
__global__ void pad_weight(const float* __restrict__ W, short* __restrict__ Wp,
                           int rows, int cols, int KP) {
    int i = blockIdx.x * 256 + threadIdx.x;
    if (i >= 80 * KP) return;
    int t = i / KP, s = i - t * KP;
    Wp[i] = (t < rows && s < cols) ? f2bf(W[t * cols + s]) : (short)0;
}

// ---------------- bf16 GEMM: C[M,N] = A[M,K] @ W[N,K]^T (+epilogue) -------------
// m97 structure: 128x128 tile, BK=64, 4 waves (each 64x64), global_load_lds w=16.
// 1-D grid + bijective XCD swizzle (m204): physical block p runs on XCD p%8, so
// we map XCD x to a CONTIGUOUS logical chunk in bn-fast/bm-major order. Each
// 128-row A-panel is then consumed entirely within one XCD -> A fetched ~once
// (R7 diagnosis: un-swizzled, the 10 blocks sharing a panel landed on 8 XCDs,
// duplicating A in every private L2: FETCH ~= 8 x 50 MB = 431 MB observed).
// EPI: 0 = +bias -> bf16 ; 1 = (+bias)*scale -> bf16 ; 2 = gelu(+bias) -> bf16 ;
//      3 = +bias -> fp32
template<int EPI>
__global__ void gemm_bt(const short* __restrict__ A, const short* __restrict__ W,
                        const float* __restrict__ bias, void* __restrict__ Cout,
                        int K, float scale) {
    const int N = E_;
    const int NBN = E_ / 128;            // 10 N-tiles
    __shared__ short Als[128 * 64];
    __shared__ short Bls[128 * 64];
    const int tid  = threadIdx.x;
    const int wave = tid >> 6, lane = tid & 63;

    // bijective XCD swizzle: XCD x = p%8 gets logical ids [x-chunk), bn-fast
    const int nwg = gridDim.x;
    const int qq = nwg >> 3, rr = nwg & 7;
    const int x = blockIdx.x & 7, ii = blockIdx.x >> 3;
    const int L = (x < rr ? x * (qq + 1) : rr * (qq + 1) + (x - rr) * qq) + ii;
    const int bm = L / NBN, bn = L % NBN;

    const int wm = (wave >> 1) * 64, wn = (wave & 1) * 64;

    f32x4 acc[4][4] = {};

    const long arow0 = (long)bm * 128;
    const long brow0 = (long)bn * 128;
    const int rsub = lane >> 3;          // 0..7 row within 8-row chunk
    const int col  = (lane & 7) * 8;     // 0..56, 8 bf16 = 16B per lane

    for (int kt = 0; kt < K; kt += 64) {
        __syncthreads();   // prev compute done before overwriting LDS
#pragma unroll
        for (int i = 0; i < 4; ++i) {
            int chunk = i * 4 + wave;          // 0..15, 8 rows each
            int row = chunk * 8 + rsub;
            const short* ga = A + (arow0 + row) * K + kt + col;
            const short* gb = W + (brow0 + row) * K + kt + col;
            __builtin_amdgcn_global_load_lds(
                (const __attribute__((address_space(1))) unsigned int*)ga,
                (__attribute__((address_space(3))) unsigned int*)&Als[chunk * 512], 16, 0, 0);
            __builtin_amdgcn_global_load_lds(
                (const __attribute__((address_space(1))) unsigned int*)gb,
                (__attribute__((address_space(3))) unsigned int*)&Bls[chunk * 512], 16, 0, 0);
        }
        __syncthreads();   // drains vmcnt -> tiles ready
#pragma unroll
        for (int kk = 0; kk < 2; ++kk) {
            bf16x8 af[4], bfr[4];
#pragma unroll
            for (int mi = 0; mi < 4; ++mi)
                af[mi] = *reinterpret_cast<const bf16x8*>(
                    &Als[(wm + mi * 16 + (lane & 15)) * 64 + kk * 32 + (lane >> 4) * 8]);
#pragma unroll
            for (int nj = 0; nj < 4; ++nj)
                bfr[nj] = *reinterpret_cast<const bf16x8*>(
                    &Bls[(wn + nj * 16 + (lane & 15)) * 64 + kk * 32 + (lane >> 4) * 8]);
#pragma unroll
            for (int mi = 0; mi < 4; ++mi)
#pragma unroll
                for (int nj = 0; nj < 4; ++nj)
                    acc[mi][nj] = __builtin_amdgcn_mfma_f32_16x16x32_bf16(
                        af[mi], bfr[nj], acc[mi][nj], 0, 0, 0);
        }
    }

    // epilogue: C/D layout col=lane&15, row=(lane>>4)*4+r  [m89-verified]
#pragma unroll
    for (int mi = 0; mi < 4; ++mi) {
#pragma unroll
        for (int nj = 0; nj < 4; ++nj) {
            int gcol = bn * 128 + wn + nj * 16 + (lane & 15);
            float bv = bias[gcol];
#pragma unroll
            for (int r = 0; r < 4; ++r) {
                long grow = arow0 + wm + mi * 16 + (lane >> 4) * 4 + r;
                float v = acc[mi][nj][r] + bv;
                if (EPI == 1) v *= scale;
                if (EPI == 2) v = gelu_tanh(v);
                if (EPI == 3) ((float*)Cout)[grow * N + gcol] = v;
                else          ((short*)Cout)[grow * N + gcol] = f2bf(v);
            }
        }
    }
}

// ---------------- MFMA token mixer ----------------
template<int SIN, int KP, int PS, bool GELU, bool RESID>
__global__ void mixer_mfma(const short* __restrict__ IN, const short* __restrict__ Wp,
                           const float* __restrict__ bias, const short* __restrict__ Cat,
                           short* __restrict__ OUT) {
    __shared__ short lsT[64 * PS];
    const int e0 = blockIdx.x * 64;
    const int b  = blockIdx.y;
    const int tid = threadIdx.x, wave = tid >> 6, lane = tid & 63;

    const int eg = tid & 7;       // which 8-e group this thread handles
    const int sl = tid >> 3;      // s row, 32 per pass
    for (int sb = sl; sb < KP; sb += 32) {
        if (sb < SIN) {
            bf16x8 v = *reinterpret_cast<const bf16x8*>(
                &IN[((long)b * SIN + sb) * E_ + e0 + eg * 8]);
#pragma unroll
            for (int i = 0; i < 8; ++i)
                lsT[(eg * 8 + i) * PS + sb] = v[i];
        } else {
#pragma unroll
            for (int i = 0; i < 8; ++i)
                lsT[(eg * 8 + i) * PS + sb] = 0;
        }
    }
    __syncthreads();

    const int ebase = wave * 16;          // e-subtile owned by this wave
    f32x4 acc[5] = {};
#pragma unroll
    for (int ks = 0; ks < KP / 32; ++ks) {
        bf16x8 bfr = *reinterpret_cast<const bf16x8*>(
            &lsT[(ebase + (lane & 15)) * PS + ks * 32 + (lane >> 4) * 8]);
#pragma unroll
        for (int mt = 0; mt < 5; ++mt) {
            bf16x8 af = *reinterpret_cast<const bf16x8*>(
                &Wp[(mt * 16 + (lane & 15)) * KP + ks * 32 + (lane >> 4) * 8]);
            acc[mt] = __builtin_amdgcn_mfma_f32_16x16x32_bf16(af, bfr, acc[mt], 0, 0, 0);
        }
    }

    const int e = e0 + ebase + (lane & 15);
#pragma unroll
    for (int mt = 0; mt < 5; ++mt) {
#pragma unroll
        for (int r = 0; r < 4; ++r) {
            int t = mt * 16 + (lane >> 4) * 4 + r;
            if (t < T_) {
                float v = acc[mt][r] + bias[t];
                if (GELU) v = gelu_tanh(v);
                if (RESID) v += bf2f(Cat[((long)b * T2_ + T_ + t) * E_ + e]);
                OUT[((long)b * T_ + t) * E_ + e] = f2bf(v);
            }
        }
    }
}

// ---------------- fused MFMA attention: one WAVE per (b,h), both passes ----------------
#define ASTR 104   // LDS row stride (shorts): 16B-aligned, <=2-way banks on b128
__global__ __launch_bounds__(64, 1)
void attn_mfma(const short* __restrict__ Qm,
               const short* __restrict__ Km, const short* __restrict__ Vm,
               const short* __restrict__ KAm, const short* __restrict__ VAm,
               short* __restrict__ Cat) {
    __shared__ short pls[80 * ASTR];
    __shared__ short vt[64 * ASTR];
    const int hh = blockIdx.x;
    const int b = hh / H_, h = hh % H_;
    const int lane = threadIdx.x & 63;
    const int colbase = lane & 15, g = lane >> 4;
    const long base = ((long)b * T_) * E_ + h * 64;

    for (int pass = 0; pass < 2; ++pass) {
        const short* Kp = pass ? KAm : Km;
        const short* Vp = pass ? VAm : Vm;
        const bool causal = (pass == 0);
        const int rowoff = pass ? 0 : T_;

        // ---- zero LDS K-tails (cols >= valid range) BEFORE staging ----
        {
            int4 z = {0, 0, 0, 0};
#pragma unroll
            for (int it = 0; it < 4; ++it) {          // vt rows 0..63, cols 64..95
                int idx = it * 64 + lane;
                int row = idx >> 2, cb = idx & 3;
                *reinterpret_cast<int4*>(&vt[row * ASTR + 64 + cb * 8]) = z;
            }
#pragma unroll
            for (int it = 0; it < 3; ++it) {          // pls rows 0..79, cols 80..95
                int idx = it * 64 + lane;
                if (idx < 160) {
                    int row = idx >> 1, cb = idx & 1;
                    *reinterpret_cast<int4*>(&pls[row * ASTR + 80 + cb * 8]) = z;
                }
            }
        }

        // ---- stage V^T: vt[d][s] = V[s][d]; lane = s (transpose writes conflict-free) ----
        {
            const short* vb = Vp + base + (long)lane * E_;
#pragma unroll
            for (int dg = 0; dg < 8; ++dg) {
                bf16x8 v = *reinterpret_cast<const bf16x8*>(vb + dg * 8);
#pragma unroll
                for (int i = 0; i < 8; ++i) vt[(dg * 8 + i) * ASTR + lane] = v[i];
            }
            if (lane < T_ - 64) {
                const short* vb2 = Vp + base + (long)(64 + lane) * E_;
#pragma unroll
                for (int dg = 0; dg < 8; ++dg) {
                    bf16x8 v = *reinterpret_cast<const bf16x8*>(vb2 + dg * 8);
#pragma unroll
                    for (int i = 0; i < 8; ++i) vt[(dg * 8 + i) * ASTR + 64 + lane] = v[i];
                }
            }
        }

        // ---- S = Q.K^T (frags from global; A/B layout = m89-verified gemm pattern) ----
        f32x4 sacc[5][5] = {};
#pragma unroll
        for (int kk = 0; kk < 2; ++kk) {
            bf16x8 qf[5];
#pragma unroll
            for (int mi = 0; mi < 5; ++mi) {
                int t = mi * 16 + colbase; t = t > 76 ? 76 : t;
                qf[mi] = *reinterpret_cast<const bf16x8*>(
                    Qm + base + (long)t * E_ + kk * 32 + g * 8);
            }
#pragma unroll
            for (int nj = 0; nj < 5; ++nj) {
                int s = nj * 16 + colbase; s = s > 76 ? 76 : s;
                bf16x8 kf = *reinterpret_cast<const bf16x8*>(
                    Kp + base + (long)s * E_ + kk * 32 + g * 8);
#pragma unroll
                for (int mi = 0; mi < 5; ++mi)
                    sacc[mi][nj] = __builtin_amdgcn_mfma_f32_16x16x32_bf16(
                        qf[mi], kf, sacc[mi][nj], 0, 0, 0);
            }
        }

        // ---- masked softmax in C-layout; row-reduce across the 16-lane group ----
        float inv[5][4];
#pragma unroll
        for (int mi = 0; mi < 5; ++mi) {
#pragma unroll
            for (int r = 0; r < 4; ++r) {
                int t = mi * 16 + g * 4 + r;
                float mx = -3.0e38f;
#pragma unroll
                for (int nj = 0; nj < 5; ++nj) {
                    int s = nj * 16 + colbase;
                    bool ok = causal ? (s <= t) : (s < T_);
                    if (ok) mx = fmaxf(mx, sacc[mi][nj][r]);
                }
#pragma unroll
                for (int o = 1; o <= 8; o <<= 1) mx = fmaxf(mx, __shfl_xor(mx, o));
                float sum = 0.f;
#pragma unroll
                for (int nj = 0; nj < 5; ++nj) {
                    int s = nj * 16 + colbase;
                    bool ok = causal ? (s <= t) : (s < T_);
                    float pv = ok ? __expf(sacc[mi][nj][r] - mx) : 0.f;
                    sacc[mi][nj][r] = pv;
                    sum += pv;
                }
#pragma unroll
                for (int o = 1; o <= 8; o <<= 1) sum += __shfl_xor(sum, o);
                inv[mi][r] = 1.0f / sum;
            }
        }

        // ---- write unnormalized P (bf16) to LDS ----
#pragma unroll
        for (int mi = 0; mi < 5; ++mi)
#pragma unroll
            for (int nj = 0; nj < 5; ++nj)
#pragma unroll
                for (int r = 0; r < 4; ++r)
                    pls[(mi * 16 + g * 4 + r) * ASTR + nj * 16 + colbase] =
                        f2bf(sacc[mi][nj][r]);

        // ---- ctx = P.V via mfma (A = P rows, B = V^T rows; K = 96) ----
        f32x4 cacc[5][4] = {};
#pragma unroll
        for (int ks = 0; ks < 3; ++ks) {
            bf16x8 pa[5];
#pragma unroll
            for (int mi = 0; mi < 5; ++mi)
                pa[mi] = *reinterpret_cast<const bf16x8*>(
                    &pls[(mi * 16 + colbase) * ASTR + ks * 32 + g * 8]);
#pragma unroll
            for (int nd = 0; nd < 4; ++nd) {
                bf16x8 vf = *reinterpret_cast<const bf16x8*>(
                    &vt[(nd * 16 + colbase) * ASTR + ks * 32 + g * 8]);
#pragma unroll
                for (int mi = 0; mi < 5; ++mi)
                    cacc[mi][nd] = __builtin_amdgcn_mfma_f32_16x16x32_bf16(
                        pa[mi], vf, cacc[mi][nd], 0, 0, 0);
            }
        }

        // ---- epilogue: normalize by 1/rowsum, write CAT ----
#pragma unroll
        for (int mi = 0; mi < 5; ++mi)
#pragma unroll
            for (int nd = 0; nd < 4; ++nd)
#pragma unroll
                for (int r = 0; r < 4; ++r) {
                    int t = mi * 16 + g * 4 + r;
                    if (t < T_) {
                        float val = cacc[mi][nd][r] * inv[mi][r];
                        Cat[((long)b * T2_ + rowoff + t) * E_ + h * 64 + nd * 16 + colbase] =
                            f2bf(val);
                    }
                }
    }
}

extern "C" void kernel_launch(void* const* d_in, const int* in_sizes, int n_in,
                              void* d_out, int out_size, void* d_ws, size_t ws_size,
                              hipStream_t stream) {
    const float* hidden = (const float*)d_in[0];
    const float* embeds = (const float*)d_in[1];
    // d_in[2] causal_mask unused (exactly triu(-1e9) -> applied analytically)
    const float* q_w  = (const float*)d_in[3];  const float* q_b  = (const float*)d_in[4];
    const float* k_w  = (const float*)d_in[5];  const float* k_b  = (const float*)d_in[6];
    const float* v_w  = (const float*)d_in[7];  const float* v_b  = (const float*)d_in[8];
    const float* o_w  = (const float*)d_in[9];  const float* o_b  = (const float*)d_in[10];
    const float* ka_w = (const float*)d_in[11]; const float* ka_b = (const float*)d_in[12];
    const float* va_w = (const float*)d_in[13]; const float* va_b = (const float*)d_in[14];
    const float* zc1_w = (const float*)d_in[15]; const float* zc1_b = (const float*)d_in[16];
    const float* zt1_w = (const float*)d_in[17]; const float* zt1_b = (const float*)d_in[18];
    const float* zc2_w = (const float*)d_in[19]; const float* zc2_b = (const float*)d_in[20];
    const float* zt2_w = (const float*)d_in[21]; const float* zt2_b = (const float*)d_in[22];

    char* ws = (char*)d_ws;
    const size_t WSZ = (size_t)E_ * E_ * 2;      // 3,276,800 B per weight
    const size_t ASZ = (size_t)MTOK * E_ * 2;    // 50,462,720 B per activation
    short* Wq  = (short*)(ws + 0 * WSZ);
    short* Wk  = (short*)(ws + 1 * WSZ);
    short* Wv  = (short*)(ws + 2 * WSZ);
    short* Wka = (short*)(ws + 3 * WSZ);
    short* Wva = (short*)(ws + 4 * WSZ);
    short* Wz1 = (short*)(ws + 5 * WSZ);
    short* Wz2 = (short*)(ws + 6 * WSZ);
    short* Wo  = (short*)(ws + 7 * WSZ);
    char* p = ws + 8 * WSZ;
    short* Ahs  = (short*)p; p += ASZ;
    short* Aemb = (short*)p; p += ASZ;
    short* Qb   = (short*)p; p += ASZ;
    short* Kb   = (short*)p; p += ASZ;
    short* Vb   = (short*)p; p += ASZ;
    short* KAb  = (short*)p; p += ASZ;
    short* VAb  = (short*)p; p += ASZ;
    short* Wz1p = (short*)p; p += 80 * 160 * 2;  // padded zt1_w bf16 [80][160]
    short* Wz2p = (short*)p; p += 80 * 96 * 2;   // padded zt2_w bf16 [80][96]
    // aliases (lifetimes disjoint in stream order):
    short* CAT = Ahs;   // (B,2T,E) over Ahs+Aemb   — written after q/k/v/ka/va GEMMs
    short* Y   = KAb;   // (B,2T,E) over KAb+VAb    — written after adapter attn
    short* X2  = Qb;    // written after both attns
    short* X3  = Kb;
    short* S   = Vb;

    if (ws_size < (size_t)(p - ws)) return;   // clean-fail signal

    // casts
    cast_f32_bf16<<<2048, 256, 0, stream>>>(hidden, Ahs,  MTOK * E_ / 4);
    cast_f32_bf16<<<2048, 256, 0, stream>>>(embeds, Aemb, MTOK * E_ / 4);
    cast_f32_bf16<<<512, 256, 0, stream>>>(q_w,  Wq,  E_ * E_ / 4);
    cast_f32_bf16<<<512, 256, 0, stream>>>(k_w,  Wk,  E_ * E_ / 4);
    cast_f32_bf16<<<512, 256, 0, stream>>>(v_w,  Wv,  E_ * E_ / 4);
    cast_f32_bf16<<<512, 256, 0, stream>>>(ka_w, Wka, E_ * E_ / 4);
    cast_f32_bf16<<<512, 256, 0, stream>>>(va_w, Wva, E_ * E_ / 4);
    cast_f32_bf16<<<512, 256, 0, stream>>>(zc1_w, Wz1, E_ * E_ / 4);
    cast_f32_bf16<<<512, 256, 0, stream>>>(zc2_w, Wz2, E_ * E_ / 4);
    cast_f32_bf16<<<512, 256, 0, stream>>>(o_w,  Wo,  E_ * E_ / 4);
    pad_weight<<<(80 * 160 + 255) / 256, 256, 0, stream>>>(zt1_w, Wz1p, 77, 154, 160);
    pad_weight<<<(80 * 96 + 255) / 256, 256, 0, stream>>>(zt2_w, Wz2p, 77, 77, 96);

    const int g154 = (MTOK / 128) * (E_ / 128);    // 1540 blocks, 1-D + swizzle
    const int g308 = (MTOK2 / 128) * (E_ / 128);   // 3080 blocks
    // projections
    gemm_bt<1><<<g154, 256, 0, stream>>>(Ahs,  Wq,  q_b,  Qb,  E_, 0.125f); // (x@Wq^T+b)*scale
    gemm_bt<0><<<g154, 256, 0, stream>>>(Ahs,  Wk,  k_b,  Kb,  E_, 1.f);
    gemm_bt<0><<<g154, 256, 0, stream>>>(Ahs,  Wv,  v_b,  Vb,  E_, 1.f);
    gemm_bt<0><<<g154, 256, 0, stream>>>(Aemb, Wka, ka_b, KAb, E_, 1.f);
    gemm_bt<0><<<g154, 256, 0, stream>>>(Aemb, Wva, va_b, VAb, E_, 1.f);
    // fused attention (both passes): adapter rows [0,77), self rows [77,154) of CAT
    attn_mfma<<<B_ * H_, 64, 0, stream>>>(Qb, Kb, Vb, KAb, VAb, CAT);
    // zipper
    gemm_bt<2><<<g308, 256, 0, stream>>>(CAT, Wz1, zc1_b, Y, E_, 1.f);      // gelu
    mixer_mfma<154, 160, 168, true, false><<<dim3(E_ / 64, B_), 256, 0, stream>>>(
        Y, Wz1p, zt1_b, nullptr, X2);
    gemm_bt<0><<<g154, 256, 0, stream>>>(X2, Wz2, zc2_b, X3, E_, 1.f);
    mixer_mfma<77, 96, 104, false, true><<<dim3(E_ / 64, B_), 256, 0, stream>>>(
        X3, Wz2p, zt2_b, CAT, S);
    // output projection -> fp32 d_out
    gemm_bt<3><<<g154, 256, 0, stream>>>(S, Wo, o_b, (float*)d_out, E_, 1.f);
}

// Round 9
// 1047.742 us; speedup vs baseline: 3.3483x; 1.0779x over previous
//
#include <hip/hip_runtime.h>
#include <stdint.h>

#define B_    256
#define T_    77
#define E_    1280
#define H_    20
#define T2_   154
#define MTOK  19712   // B_*T_
#define MTOK2 39424   // B_*T2_

typedef float f32x4 __attribute__((ext_vector_type(4)));
typedef short bf16x8 __attribute__((ext_vector_type(8)));

__device__ inline float bf2f(short s) {
    return __uint_as_float(((unsigned)(unsigned short)s) << 16);
}
__device__ inline short f2bf(float f) {
    unsigned u = __float_as_uint(f);
    u += 0x7fff + ((u >> 16) & 1);   // RNE
    return (short)(u >> 16);
}
__device__ inline float gelu_tanh(float x) {   // jax.nn.gelu approximate=True
    float x3 = x * x * x;
    return 0.5f * x * (1.0f + tanhf(0.7978845608028654f * (x + 0.044715f * x3)));
}

// ---------------- fp32 -> bf16 cast ----------------
__global__ void cast_f32_bf16(const float* __restrict__ in, short* __restrict__ out, int n4) {
    int i = blockIdx.x * blockDim.x + threadIdx.x;
    int stride = gridDim.x * blockDim.x;
    for (; i < n4; i += stride) {
        float4 v = reinterpret_cast<const float4*>(in)[i];
        short4 o;
        o.x = f2bf(v.x); o.y = f2bf(v.y); o.z = f2bf(v.z); o.w = f2bf(v.w);
        reinterpret_cast<short4*>(out)[i] = o;
    }
}

// ---------------- pad token-mix weight: fp32 (rows x cols) -> bf16 [80][KP], zero pad ----
__global__ void pad_weight(const float* __restrict__ W, short* __restrict__ Wp,
                           int rows, int cols, int KP) {
    int i = blockIdx.x * 256 + threadIdx.x;
    if (i >= 80 * KP) return;
    int t = i / KP, s = i - t * KP;
    Wp[i] = (t < rows && s < cols) ? f2bf(W[t * cols + s]) : (short)0;
}

// ---------------- bf16 GEMM: C[M,N] = A[M,K] @ W[N,K]^T (+epilogue) -------------
// m97 structure: 128x128 tile, BK=64, 4 waves (each 64x64), global_load_lds w=16.
// 1-D grid + bijective XCD swizzle (R8: FETCH 431->95 MB, kept).
// R9: LDS XOR-swizzle (T2, rule #21 both-sides): [row][64] row-major gave all 16
// lanes of a fragment read the same 4 banks (16-way conflict, 4.7e7 cy/dispatch
// = 34% of runtime). global_load_lds writes linearly, so the SOURCE global col
// is pre-permuted per lane (col = ((lane&7) ^ (lane>>3))*8) and the READ index
// XORs ((lane&7)<<3): physical = r*64 + (c ^ ((r&7)<<3)), an involution.
// Fragment rows satisfy row%8 == lane%8, so the read XOR is lane-constant.
// EPI: 0 = +bias -> bf16 ; 1 = (+bias)*scale -> bf16 ; 2 = gelu(+bias) -> bf16 ;
//      3 = +bias -> fp32
template<int EPI>
__global__ void gemm_bt(const short* __restrict__ A, const short* __restrict__ W,
                        const float* __restrict__ bias, void* __restrict__ Cout,
                        int K, float scale) {
    const int N = E_;
    const int NBN = E_ / 128;            // 10 N-tiles
    __shared__ short Als[128 * 64];
    __shared__ short Bls[128 * 64];
    const int tid  = threadIdx.x;
    const int wave = tid >> 6, lane = tid & 63;

    // bijective XCD swizzle: XCD x = p%8 gets a contiguous logical chunk, bn-fast
    const int nwg = gridDim.x;
    const int qq = nwg >> 3, rr = nwg & 7;
    const int x = blockIdx.x & 7, ii = blockIdx.x >> 3;
    const int L = (x < rr ? x * (qq + 1) : rr * (qq + 1) + (x - rr) * qq) + ii;
    const int bm = L / NBN, bn = L % NBN;

    const int wm = (wave >> 1) * 64, wn = (wave & 1) * 64;

    f32x4 acc[4][4] = {};

    const long arow0 = (long)bm * 128;
    const long brow0 = (long)bn * 128;
    const int rsub = lane >> 3;                        // 0..7 row within 8-row chunk
    const int col  = (((lane & 7) ^ rsub) & 7) * 8;    // pre-swizzled source column
    const int swz  = (lane & 7) << 3;                  // read-side XOR (shorts)

    for (int kt = 0; kt < K; kt += 64) {
        __syncthreads();   // prev compute done before overwriting LDS
#pragma unroll
        for (int i = 0; i < 4; ++i) {
            int chunk = i * 4 + wave;          // 0..15, 8 rows each
            int row = chunk * 8 + rsub;
            const short* ga = A + (arow0 + row) * K + kt + col;
            const short* gb = W + (brow0 + row) * K + kt + col;
            __builtin_amdgcn_global_load_lds(
                (const __attribute__((address_space(1))) unsigned int*)ga,
                (__attribute__((address_space(3))) unsigned int*)&Als[chunk * 512], 16, 0, 0);
            __builtin_amdgcn_global_load_lds(
                (const __attribute__((address_space(1))) unsigned int*)gb,
                (__attribute__((address_space(3))) unsigned int*)&Bls[chunk * 512], 16, 0, 0);
        }
        __syncthreads();   // drains vmcnt -> tiles ready
#pragma unroll
        for (int kk = 0; kk < 2; ++kk) {
            bf16x8 af[4], bfr[4];
#pragma unroll
            for (int mi = 0; mi < 4; ++mi)
                af[mi] = *reinterpret_cast<const bf16x8*>(
                    &Als[(((wm + mi * 16 + (lane & 15)) * 64 + kk * 32 + (lane >> 4) * 8)) ^ swz]);
#pragma unroll
            for (int nj = 0; nj < 4; ++nj)
                bfr[nj] = *reinterpret_cast<const bf16x8*>(
                    &Bls[(((wn + nj * 16 + (lane & 15)) * 64 + kk * 32 + (lane >> 4) * 8)) ^ swz]);
#pragma unroll
            for (int mi = 0; mi < 4; ++mi)
#pragma unroll
                for (int nj = 0; nj < 4; ++nj)
                    acc[mi][nj] = __builtin_amdgcn_mfma_f32_16x16x32_bf16(
                        af[mi], bfr[nj], acc[mi][nj], 0, 0, 0);
        }
    }

    // epilogue: C/D layout col=lane&15, row=(lane>>4)*4+r  [m89-verified]
#pragma unroll
    for (int mi = 0; mi < 4; ++mi) {
#pragma unroll
        for (int nj = 0; nj < 4; ++nj) {
            int gcol = bn * 128 + wn + nj * 16 + (lane & 15);
            float bv = bias[gcol];
#pragma unroll
            for (int r = 0; r < 4; ++r) {
                long grow = arow0 + wm + mi * 16 + (lane >> 4) * 4 + r;
                float v = acc[mi][nj][r] + bv;
                if (EPI == 1) v *= scale;
                if (EPI == 2) v = gelu_tanh(v);
                if (EPI == 3) ((float*)Cout)[grow * N + gcol] = v;
                else          ((short*)Cout)[grow * N + gcol] = f2bf(v);
            }
        }
    }
}

// ---------------- MFMA token mixer ----------------
template<int SIN, int KP, int PS, bool GELU, bool RESID>
__global__ void mixer_mfma(const short* __restrict__ IN, const short* __restrict__ Wp,
                           const float* __restrict__ bias, const short* __restrict__ Cat,
                           short* __restrict__ OUT) {
    __shared__ short lsT[64 * PS];
    const int e0 = blockIdx.x * 64;
    const int b  = blockIdx.y;
    const int tid = threadIdx.x, wave = tid >> 6, lane = tid & 63;

    const int eg = tid & 7;       // which 8-e group this thread handles
    const int sl = tid >> 3;      // s row, 32 per pass
    for (int sb = sl; sb < KP; sb += 32) {
        if (sb < SIN) {
            bf16x8 v = *reinterpret_cast<const bf16x8*>(
                &IN[((long)b * SIN + sb) * E_ + e0 + eg * 8]);
#pragma unroll
            for (int i = 0; i < 8; ++i)
                lsT[(eg * 8 + i) * PS + sb] = v[i];
        } else {
#pragma unroll
            for (int i = 0; i < 8; ++i)
                lsT[(eg * 8 + i) * PS + sb] = 0;
        }
    }
    __syncthreads();

    const int ebase = wave * 16;          // e-subtile owned by this wave
    f32x4 acc[5] = {};
#pragma unroll
    for (int ks = 0; ks < KP / 32; ++ks) {
        bf16x8 bfr = *reinterpret_cast<const bf16x8*>(
            &lsT[(ebase + (lane & 15)) * PS + ks * 32 + (lane >> 4) * 8]);
#pragma unroll
        for (int mt = 0; mt < 5; ++mt) {
            bf16x8 af = *reinterpret_cast<const bf16x8*>(
                &Wp[(mt * 16 + (lane & 15)) * KP + ks * 32 + (lane >> 4) * 8]);
            acc[mt] = __builtin_amdgcn_mfma_f32_16x16x32_bf16(af, bfr, acc[mt], 0, 0, 0);
        }
    }

    const int e = e0 + ebase + (lane & 15);
#pragma unroll
    for (int mt = 0; mt < 5; ++mt) {
#pragma unroll
        for (int r = 0; r < 4; ++r) {
            int t = mt * 16 + (lane >> 4) * 4 + r;
            if (t < T_) {
                float v = acc[mt][r] + bias[t];
                if (GELU) v = gelu_tanh(v);
                if (RESID) v += bf2f(Cat[((long)b * T2_ + T_ + t) * E_ + e]);
                OUT[((long)b * T_ + t) * E_ + e] = f2bf(v);
            }
        }
    }
}

// ---------------- fused MFMA attention: one WAVE per (b,h), both passes ----------------
#define ASTR 104   // LDS row stride (shorts): 16B-aligned, <=2-way banks on b128
__global__ __launch_bounds__(64, 1)
void attn_mfma(const short* __restrict__ Qm,
               const short* __restrict__ Km, const short* __restrict__ Vm,
               const short* __restrict__ KAm, const short* __restrict__ VAm,
               short* __restrict__ Cat) {
    __shared__ short pls[80 * ASTR];
    __shared__ short vt[64 * ASTR];
    const int hh = blockIdx.x;
    const int b = hh / H_, h = hh % H_;
    const int lane = threadIdx.x & 63;
    const int colbase = lane & 15, g = lane >> 4;
    const long base = ((long)b * T_) * E_ + h * 64;

    for (int pass = 0; pass < 2; ++pass) {
        const short* Kp = pass ? KAm : Km;
        const short* Vp = pass ? VAm : Vm;
        const bool causal = (pass == 0);
        const int rowoff = pass ? 0 : T_;

        // ---- zero LDS K-tails (cols >= valid range) BEFORE staging ----
        {
            int4 z = {0, 0, 0, 0};
#pragma unroll
            for (int it = 0; it < 4; ++it) {          // vt rows 0..63, cols 64..95
                int idx = it * 64 + lane;
                int row = idx >> 2, cb = idx & 3;
                *reinterpret_cast<int4*>(&vt[row * ASTR + 64 + cb * 8]) = z;
            }
#pragma unroll
            for (int it = 0; it < 3; ++it) {          // pls rows 0..79, cols 80..95
                int idx = it * 64 + lane;
                if (idx < 160) {
                    int row = idx >> 1, cb = idx & 1;
                    *reinterpret_cast<int4*>(&pls[row * ASTR + 80 + cb * 8]) = z;
                }
            }
        }

        // ---- stage V^T: vt[d][s] = V[s][d]; lane = s (transpose writes conflict-free) ----
        {
            const short* vb = Vp + base + (long)lane * E_;
#pragma unroll
            for (int dg = 0; dg < 8; ++dg) {
                bf16x8 v = *reinterpret_cast<const bf16x8*>(vb + dg * 8);
#pragma unroll
                for (int i = 0; i < 8; ++i) vt[(dg * 8 + i) * ASTR + lane] = v[i];
            }
            if (lane < T_ - 64) {
                const short* vb2 = Vp + base + (long)(64 + lane) * E_;
#pragma unroll
                for (int dg = 0; dg < 8; ++dg) {
                    bf16x8 v = *reinterpret_cast<const bf16x8*>(vb2 + dg * 8);
#pragma unroll
                    for (int i = 0; i < 8; ++i) vt[(dg * 8 + i) * ASTR + 64 + lane] = v[i];
                }
            }
        }

        // ---- S = Q.K^T (frags from global; A/B layout = m89-verified gemm pattern) ----
        f32x4 sacc[5][5] = {};
#pragma unroll
        for (int kk = 0; kk < 2; ++kk) {
            bf16x8 qf[5];
#pragma unroll
            for (int mi = 0; mi < 5; ++mi) {
                int t = mi * 16 + colbase; t = t > 76 ? 76 : t;
                qf[mi] = *reinterpret_cast<const bf16x8*>(
                    Qm + base + (long)t * E_ + kk * 32 + g * 8);
            }
#pragma unroll
            for (int nj = 0; nj < 5; ++nj) {
                int s = nj * 16 + colbase; s = s > 76 ? 76 : s;
                bf16x8 kf = *reinterpret_cast<const bf16x8*>(
                    Kp + base + (long)s * E_ + kk * 32 + g * 8);
#pragma unroll
                for (int mi = 0; mi < 5; ++mi)
                    sacc[mi][nj] = __builtin_amdgcn_mfma_f32_16x16x32_bf16(
                        qf[mi], kf, sacc[mi][nj], 0, 0, 0);
            }
        }

        // ---- masked softmax in C-layout; row-reduce across the 16-lane group ----
        float inv[5][4];
#pragma unroll
        for (int mi = 0; mi < 5; ++mi) {
#pragma unroll
            for (int r = 0; r < 4; ++r) {
                int t = mi * 16 + g * 4 + r;
                float mx = -3.0e38f;
#pragma unroll
                for (int nj = 0; nj < 5; ++nj) {
                    int s = nj * 16 + colbase;
                    bool ok = causal ? (s <= t) : (s < T_);
                    if (ok) mx = fmaxf(mx, sacc[mi][nj][r]);
                }
#pragma unroll
                for (int o = 1; o <= 8; o <<= 1) mx = fmaxf(mx, __shfl_xor(mx, o));
                float sum = 0.f;
#pragma unroll
                for (int nj = 0; nj < 5; ++nj) {
                    int s = nj * 16 + colbase;
                    bool ok = causal ? (s <= t) : (s < T_);
                    float pv = ok ? __expf(sacc[mi][nj][r] - mx) : 0.f;
                    sacc[mi][nj][r] = pv;
                    sum += pv;
                }
#pragma unroll
                for (int o = 1; o <= 8; o <<= 1) sum += __shfl_xor(sum, o);
                inv[mi][r] = 1.0f / sum;
            }
        }

        // ---- write unnormalized P (bf16) to LDS ----
#pragma unroll
        for (int mi = 0; mi < 5; ++mi)
#pragma unroll
            for (int nj = 0; nj < 5; ++nj)
#pragma unroll
                for (int r = 0; r < 4; ++r)
                    pls[(mi * 16 + g * 4 + r) * ASTR + nj * 16 + colbase] =
                        f2bf(sacc[mi][nj][r]);

        // ---- ctx = P.V via mfma (A = P rows, B = V^T rows; K = 96) ----
        f32x4 cacc[5][4] = {};
#pragma unroll
        for (int ks = 0; ks < 3; ++ks) {
            bf16x8 pa[5];
#pragma unroll
            for (int mi = 0; mi < 5; ++mi)
                pa[mi] = *reinterpret_cast<const bf16x8*>(
                    &pls[(mi * 16 + colbase) * ASTR + ks * 32 + g * 8]);
#pragma unroll
            for (int nd = 0; nd < 4; ++nd) {
                bf16x8 vf = *reinterpret_cast<const bf16x8*>(
                    &vt[(nd * 16 + colbase) * ASTR + ks * 32 + g * 8]);
#pragma unroll
                for (int mi = 0; mi < 5; ++mi)
                    cacc[mi][nd] = __builtin_amdgcn_mfma_f32_16x16x32_bf16(
                        pa[mi], vf, cacc[mi][nd], 0, 0, 0);
            }
        }

        // ---- epilogue: normalize by 1/rowsum, write CAT ----
#pragma unroll
        for (int mi = 0; mi < 5; ++mi)
#pragma unroll
            for (int nd = 0; nd < 4; ++nd)
#pragma unroll
                for (int r = 0; r < 4; ++r) {
                    int t = mi * 16 + g * 4 + r;
                    if (t < T_) {
                        float val = cacc[mi][nd][r] * inv[mi][r];
                        Cat[((long)b * T2_ + rowoff + t) * E_ + h * 64 + nd * 16 + colbase] =
                            f2bf(val);
                    }
                }
    }
}

extern "C" void kernel_launch(void* const* d_in, const int* in_sizes, int n_in,
                              void* d_out, int out_size, void* d_ws, size_t ws_size,
                              hipStream_t stream) {
    const float* hidden = (const float*)d_in[0];
    const float* embeds = (const float*)d_in[1];
    // d_in[2] causal_mask unused (exactly triu(-1e9) -> applied analytically)
    const float* q_w  = (const float*)d_in[3];  const float* q_b  = (const float*)d_in[4];
    const float* k_w  = (const float*)d_in[5];  const float* k_b  = (const float*)d_in[6];
    const float* v_w  = (const float*)d_in[7];  const float* v_b  = (const float*)d_in[8];
    const float* o_w  = (const float*)d_in[9];  const float* o_b  = (const float*)d_in[10];
    const float* ka_w = (const float*)d_in[11]; const float* ka_b = (const float*)d_in[12];
    const float* va_w = (const float*)d_in[13]; const float* va_b = (const float*)d_in[14];
    const float* zc1_w = (const float*)d_in[15]; const float* zc1_b = (const float*)d_in[16];
    const float* zt1_w = (const float*)d_in[17]; const float* zt1_b = (const float*)d_in[18];
    const float* zc2_w = (const float*)d_in[19]; const float* zc2_b = (const float*)d_in[20];
    const float* zt2_w = (const float*)d_in[21]; const float* zt2_b = (const float*)d_in[22];

    char* ws = (char*)d_ws;
    const size_t WSZ = (size_t)E_ * E_ * 2;      // 3,276,800 B per weight
    const size_t ASZ = (size_t)MTOK * E_ * 2;    // 50,462,720 B per activation
    short* Wq  = (short*)(ws + 0 * WSZ);
    short* Wk  = (short*)(ws + 1 * WSZ);
    short* Wv  = (short*)(ws + 2 * WSZ);
    short* Wka = (short*)(ws + 3 * WSZ);
    short* Wva = (short*)(ws + 4 * WSZ);
    short* Wz1 = (short*)(ws + 5 * WSZ);
    short* Wz2 = (short*)(ws + 6 * WSZ);
    short* Wo  = (short*)(ws + 7 * WSZ);
    char* p = ws + 8 * WSZ;
    short* Ahs  = (short*)p; p += ASZ;
    short* Aemb = (short*)p; p += ASZ;
    short* Qb   = (short*)p; p += ASZ;
    short* Kb   = (short*)p; p += ASZ;
    short* Vb   = (short*)p; p += ASZ;
    short* KAb  = (short*)p; p += ASZ;
    short* VAb  = (short*)p; p += ASZ;
    short* Wz1p = (short*)p; p += 80 * 160 * 2;  // padded zt1_w bf16 [80][160]
    short* Wz2p = (short*)p; p += 80 * 96 * 2;   // padded zt2_w bf16 [80][96]
    // aliases (lifetimes disjoint in stream order):
    short* CAT = Ahs;   // (B,2T,E) over Ahs+Aemb   — written after q/k/v/ka/va GEMMs
    short* Y   = KAb;   // (B,2T,E) over KAb+VAb    — written after adapter attn
    short* X2  = Qb;    // written after both attns
    short* X3  = Kb;
    short* S   = Vb;

    if (ws_size < (size_t)(p - ws)) return;   // clean-fail signal

    // casts
    cast_f32_bf16<<<2048, 256, 0, stream>>>(hidden, Ahs,  MTOK * E_ / 4);
    cast_f32_bf16<<<2048, 256, 0, stream>>>(embeds, Aemb, MTOK * E_ / 4);
    cast_f32_bf16<<<512, 256, 0, stream>>>(q_w,  Wq,  E_ * E_ / 4);
    cast_f32_bf16<<<512, 256, 0, stream>>>(k_w,  Wk,  E_ * E_ / 4);
    cast_f32_bf16<<<512, 256, 0, stream>>>(v_w,  Wv,  E_ * E_ / 4);
    cast_f32_bf16<<<512, 256, 0, stream>>>(ka_w, Wka, E_ * E_ / 4);
    cast_f32_bf16<<<512, 256, 0, stream>>>(va_w, Wva, E_ * E_ / 4);
    cast_f32_bf16<<<512, 256, 0, stream>>>(zc1_w, Wz1, E_ * E_ / 4);
    cast_f32_bf16<<<512, 256, 0, stream>>>(zc2_w, Wz2, E_ * E_ / 4);
    cast_f32_bf16<<<512, 256, 0, stream>>>(o_w,  Wo,  E_ * E_ / 4);
    pad_weight<<<(80 * 160 + 255) / 256, 256, 0, stream>>>(zt1_w, Wz1p, 77, 154, 160);
    pad_weight<<<(80 * 96 + 255) / 256, 256, 0, stream>>>(zt2_w, Wz2p, 77, 77, 96);

    const int g154 = (MTOK / 128) * (E_ / 128);    // 1540 blocks, 1-D + swizzle
    const int g308 = (MTOK2 / 128) * (E_ / 128);   // 3080 blocks
    // projections
    gemm_bt<1><<<g154, 256, 0, stream>>>(Ahs,  Wq,  q_b,  Qb,  E_, 0.125f); // (x@Wq^T+b)*scale
    gemm_bt<0><<<g154, 256, 0, stream>>>(Ahs,  Wk,  k_b,  Kb,  E_, 1.f);
    gemm_bt<0><<<g154, 256, 0, stream>>>(Ahs,  Wv,  v_b,  Vb,  E_, 1.f);
    gemm_bt<0><<<g154, 256, 0, stream>>>(Aemb, Wka, ka_b, KAb, E_, 1.f);
    gemm_bt<0><<<g154, 256, 0, stream>>>(Aemb, Wva, va_b, VAb, E_, 1.f);
    // fused attention (both passes): adapter rows [0,77), self rows [77,154) of CAT
    attn_mfma<<<B_ * H_, 64, 0, stream>>>(Qb, Kb, Vb, KAb, VAb, CAT);
    // zipper
    gemm_bt<2><<<g308, 256, 0, stream>>>(CAT, Wz1, zc1_b, Y, E_, 1.f);      // gelu
    mixer_mfma<154, 160, 168, true, false><<<dim3(E_ / 64, B_), 256, 0, stream>>>(
        Y, Wz1p, zt1_b, nullptr, X2);
    gemm_bt<0><<<g154, 256, 0, stream>>>(X2, Wz2, zc2_b, X3, E_, 1.f);
    mixer_mfma<77, 96, 104, false, true><<<dim3(E_ / 64, B_), 256, 0, stream>>>(
        X3, Wz2p, zt2_b, CAT, S);
    // output projection -> fp32 d_out
    gemm_bt<3><<<g154, 256, 0, stream>>>(S, Wo, o_b, (float*)d_out, E_, 1.f);
}